// Round 4
// baseline (837.612 us; speedup 1.0000x reference)
//
#include <hip/hip_runtime.h>
#include <math.h>

typedef unsigned short ushort_t;
typedef __attribute__((ext_vector_type(8))) short short8;
typedef __attribute__((ext_vector_type(16))) float f32x16;

#define B_TOTAL 131072

// ws layout (ushort element offsets). All W blobs are chunk-major, each chunk
// [32 n-rows][KC k], 16B-slot XOR-swizzled: element (r, kin) holds source
// k = ((kin>>3) ^ (r&7))*8 + (kin&7). Staged linearly via global_load_lds.
#define OFF_VIB 0        // 6 chunks  [32][64]   = 12288
#define OFF_ACO 12288    // 12 chunks [32][128]  = 49152 (kh-major: 6 per kh)
#define OFF_TMP 61440    // 6 chunks  [32][128]  = 24576
#define OFF_FUS 86016    // 18 chunks [32][192]  = 110592 (part-major)
#define OFF_WQ 196608    // 18 chunks (layer-major)
#define OFF_WO 307200    // 18 chunks
#define OFF_GRID 417792  // 2 chunks  [32][192]  = 12288
#define OFF_KV 430080    // 3 layers x 9216: Kb[4h][32s][48k] (6144) + Vt[4h][48d][16s] (3072)
#define F32_BYTE_OFF 915456
// f32 region: ggn[64], cnt[64]

__device__ __forceinline__ ushort_t f2bu(float f) {
  union { float f; unsigned u; } c; c.f = f;
  unsigned u = c.u;
  unsigned r = (u + 0x7fffu + ((u >> 16) & 1u)) >> 16;  // RTNE
  return (ushort_t)r;
}
__device__ __forceinline__ float fastrcp(float x) { return __builtin_amdgcn_rcpf(x); }
__device__ __forceinline__ float gelu_fast(float x) {
  float u = 0.7978845608f * x * (1.0f + 0.044715f * x * x);
  float E = exp2f(2.88539008f * u);
  float t = 1.0f - 2.0f * fastrcp(E + 1.0f);
  return 0.5f * x * (1.0f + t);
}
__device__ __forceinline__ f32x16 zero16() {
  f32x16 z;
#pragma unroll
  for (int i = 0; i < 16; ++i) z[i] = 0.f;
  return z;
}
#define MFMA32(a, b, c) __builtin_amdgcn_mfma_f32_32x32x16_bf16(a, b, c, 0, 0, 0)

__device__ __forceinline__ void gload16(const void* g, void* l) {
  __builtin_amdgcn_global_load_lds((const __attribute__((address_space(1))) void*)g,
                                   (__attribute__((address_space(3))) void*)l, 16, 0, 0);
}

// ---------------- prep: weights -> chunk-major swizzled bf16 ----------------
__global__ void prep_weights(const float* __restrict__ ev, const float* __restrict__ ea,
                             const float* __restrict__ et, const float* __restrict__ fw,
                             const float* __restrict__ rwq, const float* __restrict__ rwo,
                             const float* __restrict__ gr, ushort_t* __restrict__ ws) {
  int tid = blockIdx.x * blockDim.x + threadIdx.x;
  int nth = gridDim.x * blockDim.x;
  // vib: 6 chunks [32][64]
  for (int i = tid; i < 12288; i += nth) {
    int c = i >> 11, rem = i & 2047, r = rem >> 6, kin = rem & 63;
    int k = (((kin >> 3) ^ (r & 7)) << 3) + (kin & 7);
    int n = c * 32 + r;
    ws[OFF_VIB + i] = f2bu(ev[k * 192 + n]);
  }
  // aco: 12 chunks [32][128], kh-major
  for (int i = tid; i < 49152; i += nth) {
    int c = i >> 12, rem = i & 4095, r = rem >> 7, kin = rem & 127;
    int ks = (((kin >> 3) ^ (r & 7)) << 3) + (kin & 7);
    int kh = c / 6, cc = c - kh * 6;
    int n = cc * 32 + r, k = kh * 128 + ks;
    ws[OFF_ACO + i] = f2bu(ea[k * 192 + n]);
  }
  // tmp: 6 chunks [32][128]
  for (int i = tid; i < 24576; i += nth) {
    int c = i >> 12, rem = i & 4095, r = rem >> 7, kin = rem & 127;
    int ks = (((kin >> 3) ^ (r & 7)) << 3) + (kin & 7);
    int n = c * 32 + r;
    ws[OFF_TMP + i] = f2bu(et[ks * 192 + n]);
  }
  // fus: 18 chunks [32][192], part-major
  for (int i = tid; i < 110592; i += nth) {
    int c = i / 6144, rem = i - c * 6144, r = rem / 192, kin = rem - r * 192;
    int ks = (((kin >> 3) ^ (r & 7)) << 3) + (kin & 7);
    int p = c / 6, cc = c - p * 6;
    int n = cc * 32 + r;
    ws[OFF_FUS + i] = f2bu(fw[(p * 192 + ks) * 192 + n]);
  }
  // wq / wo: 18 chunks each, layer-major
  for (int i = tid; i < 110592; i += nth) {
    int c = i / 6144, rem = i - c * 6144, r = rem / 192, kin = rem - r * 192;
    int ks = (((kin >> 3) ^ (r & 7)) << 3) + (kin & 7);
    int l = c / 6, cc = c - l * 6;
    int n = cc * 32 + r;
    ws[OFF_WQ + i] = f2bu(rwq[l * 36864 + ks * 192 + n]);
    ws[OFF_WO + i] = f2bu(rwo[l * 36864 + ks * 192 + n]);
  }
  // grid: 2 chunks [32][192]
  for (int i = tid; i < 12288; i += nth) {
    int c = i / 6144, rem = i - c * 6144, r = rem / 192, kin = rem - r * 192;
    int ks = (((kin >> 3) ^ (r & 7)) << 3) + (kin & 7);
    int gidx = c * 32 + r;
    ws[OFF_GRID + i] = f2bu(gr[gidx * 192 + ks]);
  }
}

// ---------------- prep: K/V banks (bf16 operand layouts), grid norms -------
__global__ void prep_kv(const float* __restrict__ rwk, const float* __restrict__ rwv,
                        const float* __restrict__ rbk, const float* __restrict__ rbv,
                        const float* __restrict__ rmem, const float* __restrict__ gr,
                        ushort_t* __restrict__ kvf, float* __restrict__ ggn,
                        unsigned* __restrict__ cnt) {
  int tid = blockIdx.x * blockDim.x + threadIdx.x;
  int nth = gridDim.x * blockDim.x;
  // Kb[i][h][s(32, pad>=16)][k(48)]
  for (int idx = tid; idx < 18432; idx += nth) {
    int i = idx / 6144, rem = idx % 6144;
    int h = rem / 1536, r2 = rem % 1536;
    int s = r2 / 48, k = r2 % 48;
    float val = 0.f;
    if (s < 16) {
      int d = h * 48 + k;
      const float* w = rwk + i * 36864;
      const float* mm = rmem + i * 3072 + s * 192;
      float acc = rbk[i * 192 + d];
      for (int kk = 0; kk < 192; ++kk) acc += mm[kk] * w[kk * 192 + d];
      val = acc;
    }
    kvf[i * 9216 + h * 1536 + s * 48 + k] = f2bu(val);
  }
  // Vt[i][h][d(48)][s(16)]
  for (int idx = tid; idx < 9216; idx += nth) {
    int i = idx / 3072, rem = idx % 3072;
    int h = rem / 768, r2 = rem % 768;
    int d = r2 / 16, s = r2 % 16;
    int dd = h * 48 + d;
    const float* w = rwv + i * 36864;
    const float* mm = rmem + i * 3072 + s * 192;
    float acc = rbv[i * 192 + dd];
    for (int kk = 0; kk < 192; ++kk) acc += mm[kk] * w[kk * 192 + dd];
    kvf[i * 9216 + 6144 + h * 768 + d * 16 + s] = f2bu(acc);
  }
  for (int g = tid; g < 64; g += nth) {
    const float* gp = gr + g * 192;
    float s = 0.f;
    for (int k = 0; k < 192; ++k) s += gp[k] * gp[k];
    ggn[g] = s;
    cnt[g] = 0u;
  }
}

// ---------------- main-kernel helpers ----------------
__device__ __forceinline__ void stage_to(ushort_t* dst, const ushort_t* src, int n16, int wave, int lane) {
  for (int j = 0; j < n16; ++j) {
    int seg = (wave * n16 + j) << 9;  // *512 ushorts = 1KB per wave-issue
    gload16(src + seg + lane * 8, dst + seg);
  }
}

// phase stream: g -> (ws chunk pointer, 1KB-per-wave issue count)
__device__ __forceinline__ const ushort_t* chunk_ptr(const ushort_t* wsu, int g, int* n16) {
  if (g < 6)            { *n16 = 1; return wsu + OFF_VIB + g * 2048; }
  g -= 6;  if (g < 6)   { *n16 = 3; return wsu + OFF_FUS + g * 6144; }
  g -= 6;  if (g < 12)  { *n16 = 2; return wsu + OFF_ACO + g * 4096; }
  g -= 12; if (g < 6)   { *n16 = 3; return wsu + OFF_FUS + 36864 + g * 6144; }
  g -= 6;  if (g < 6)   { *n16 = 2; return wsu + OFF_TMP + g * 4096; }
  g -= 6;  if (g < 6)   { *n16 = 3; return wsu + OFF_FUS + 73728 + g * 6144; }
  g -= 6;  if (g < 36)  { int l = g / 12, r2 = g - l * 12;
    *n16 = 3;
    return (r2 < 6) ? (wsu + OFF_WQ + l * 36864 + r2 * 6144)
                    : (wsu + OFF_WO + l * 36864 + (r2 - 6) * 6144); }
  g -= 36; if (g < 2)   { *n16 = 3; return wsu + OFF_GRID + g * 6144; }
  *n16 = 0; return wsu;
}

// MFMA over one staged W chunk, A from registers
template<int KSTEPS>
__device__ __forceinline__ void mma_chunkW(const ushort_t* Wc, const short8* af, f32x16* acc, int c31, int half) {
#pragma unroll
  for (int ks = 0; ks < KSTEPS; ++ks) {
    short8 b = *(const short8*)(Wc + c31 * (KSTEPS * 16) + ((((ks * 2 + half) ^ (c31 & 7))) << 3));
    *acc = MFMA32(af[ks], b, *acc);
  }
}
// MFMA, A read per-step from Abuf panel (KSTEPS must be 12: strides coincide)
__device__ __forceinline__ void mma_chunkAW(const ushort_t* A, const ushort_t* W, f32x16* acc, int c31, int half) {
#pragma unroll
  for (int ks = 0; ks < 12; ++ks) {
    int off = c31 * 192 + ((((ks * 2 + half) ^ (c31 & 7))) << 3);
    short8 a = *(const short8*)(A + off);
    short8 b = *(const short8*)(W + off);
    *acc = MFMA32(a, b, *acc);
  }
}

template<int KSTEPS>
__device__ __forceinline__ void load_areg_glb(const float* __restrict__ x, int row, int kfull, int koff,
                                              short8* af, int half) {
  const float* p = x + (size_t)row * kfull + koff + half * 8;
#pragma unroll
  for (int ks = 0; ks < KSTEPS; ++ks) {
    float4 a = *(const float4*)(p + ks * 16);
    float4 b = *(const float4*)(p + ks * 16 + 4);
    short8 v;
    v[0] = (short)f2bu(a.x); v[1] = (short)f2bu(a.y); v[2] = (short)f2bu(a.z); v[3] = (short)f2bu(a.w);
    v[4] = (short)f2bu(b.x); v[5] = (short)f2bu(b.y); v[6] = (short)f2bu(b.z); v[7] = (short)f2bu(b.w);
    af[ks] = v;
  }
}

__device__ __forceinline__ void load_areg_lds(const ushort_t* A, short8* af, int c31, int half) {
#pragma unroll
  for (int ks = 0; ks < 12; ++ks)
    af[ks] = *(const short8*)(A + c31 * 192 + ((((ks * 2 + half) ^ (c31 & 7))) << 3));
}

// LN + GELU epilogue for 32x32 D-layout; writes swizzled bf16 into wave panel
__device__ __forceinline__ void ln_gelu_store32(f32x16* acc, const float* __restrict__ bias,
                                                const float* __restrict__ gam, const float* __restrict__ bet,
                                                ushort_t* __restrict__ A, int c31, int half) {
#pragma unroll
  for (int t = 0; t < 6; ++t) {
    float bv = bias[t * 32 + c31];
#pragma unroll
    for (int r = 0; r < 16; ++r) acc[t][r] += bv;
  }
  float s1[16], s2[16];
#pragma unroll
  for (int r = 0; r < 16; ++r) {
    float a0 = 0.f, a1 = 0.f;
#pragma unroll
    for (int t = 0; t < 6; ++t) { float x = acc[t][r]; a0 += x; a1 += x * x; }
#pragma unroll
    for (int off = 1; off < 32; off <<= 1) {
      a0 += __shfl_xor(a0, off, 64);
      a1 += __shfl_xor(a1, off, 64);
    }
    float mean = a0 * (1.0f / 192.0f);
    float var = a1 * (1.0f / 192.0f) - mean * mean;
    s1[r] = mean;
    s2[r] = rsqrtf(var + 1e-5f);
  }
#pragma unroll
  for (int t = 0; t < 6; ++t) {
    int col = t * 32 + c31;
    float ga = gam[col], be = bet[col];
#pragma unroll
    for (int r = 0; r < 16; ++r) {
      float y = (acc[t][r] - s1[r]) * s2[r] * ga + be;
      int row = (r & 3) + 8 * (r >> 2) + 4 * half;
      A[row * 192 + (((col >> 3) ^ (row & 7)) << 3) + (col & 7)] = f2bu(gelu_fast(y));
    }
  }
}

__device__ __forceinline__ void bias_store32(f32x16* acc, const float* __restrict__ bias,
                                             ushort_t* __restrict__ A, int c31, int half) {
#pragma unroll
  for (int t = 0; t < 6; ++t) {
    int col = t * 32 + c31;
    float bv = bias[col];
#pragma unroll
    for (int r = 0; r < 16; ++r) {
      int row = (r & 3) + 8 * (r >> 2) + 4 * half;
      A[row * 192 + (((col >> 3) ^ (row & 7)) << 3) + (col & 7)] = f2bu(acc[t][r] + bv);
    }
  }
}

// ---------------- main fused kernel ----------------
__global__ __launch_bounds__(256, 2) void arn_main(
    const float* __restrict__ xv, const float* __restrict__ xa, const float* __restrict__ xt,
    const ushort_t* __restrict__ wsu, const ushort_t* __restrict__ kvf,
    const float* __restrict__ ggn, unsigned* __restrict__ counts,
    const float* __restrict__ ebv, const float* __restrict__ egv, const float* __restrict__ ebbv,
    const float* __restrict__ eba, const float* __restrict__ ega, const float* __restrict__ ebba,
    const float* __restrict__ ebt, const float* __restrict__ egt, const float* __restrict__ ebbt,
    const float* __restrict__ fb, const float* __restrict__ fg, const float* __restrict__ fbb,
    const float* __restrict__ rbq, const float* __restrict__ rbo) {
  __shared__ __align__(16) ushort_t Abuf[128 * 192];  // swizzled activations (wave-private panels)
  __shared__ __align__(16) ushort_t Wbuf[2][6144];    // double-buffered W chunks
  __shared__ __align__(16) ushort_t Pbuf[4][512];     // per-wave softmax P [32 rows][16 slots]
  __shared__ float c_l[64];
  __shared__ unsigned hist[64];

  const int tid = threadIdx.x, lane = tid & 63, wave = tid >> 6;
  const int c31 = lane & 31, half = lane >> 5;
  const int myrow = blockIdx.x * 128 + wave * 32 + c31;
  ushort_t* A = Abuf + wave * 32 * 192;
  ushort_t* Pw = Pbuf[wave];

  if (tid < 64) { hist[tid] = 0u; c_l[tid] = 0.5f * ggn[tid]; }

  int gph = 0, bufc = 0;
  { int n16s; const ushort_t* s0 = chunk_ptr(wsu, 0, &n16s); stage_to(Wbuf[0], s0, n16s, wave, lane); }

#define PH_BEGIN() { __syncthreads(); int n16s; const ushort_t* nsrc = chunk_ptr(wsu, gph + 1, &n16s); \
                     if (n16s) stage_to(Wbuf[bufc ^ 1], nsrc, n16s, wave, lane); }
#define PH_END()   { bufc ^= 1; ++gph; }

  f32x16 accF[6];

  // ===== vib encoder (K=64) + fus part 0 =====
  {
    short8 af[4];
    load_areg_glb<4>(xv, myrow, 64, 0, af, half);
    f32x16 accE[6];
#pragma unroll
    for (int c = 0; c < 6; ++c) {
      PH_BEGIN();
      accE[c] = zero16();
      mma_chunkW<4>(Wbuf[bufc], af, &accE[c], c31, half);
      PH_END();
    }
    ln_gelu_store32(accE, ebv, egv, ebbv, A, c31, half);
#pragma unroll
    for (int c = 0; c < 6; ++c) {
      PH_BEGIN();
      accF[c] = zero16();
      mma_chunkAW(A, Wbuf[bufc], &accF[c], c31, half);
      PH_END();
    }
  }
  // ===== aco encoder (K=256, two kh halves) + fus part 1 =====
  {
    f32x16 accE[6];
#pragma unroll
    for (int kh = 0; kh < 2; ++kh) {
      short8 af[8];
      load_areg_glb<8>(xa, myrow, 256, kh * 128, af, half);
#pragma unroll
      for (int c = 0; c < 6; ++c) {
        PH_BEGIN();
        if (kh == 0) accE[c] = zero16();
        mma_chunkW<8>(Wbuf[bufc], af, &accE[c], c31, half);
        PH_END();
      }
    }
    ln_gelu_store32(accE, eba, ega, ebba, A, c31, half);
#pragma unroll
    for (int c = 0; c < 6; ++c) {
      PH_BEGIN();
      mma_chunkAW(A, Wbuf[bufc], &accF[c], c31, half);
      PH_END();
    }
  }
  // ===== tmp encoder (K=128) + fus part 2 + fusion LN =====
  {
    short8 af[8];
    load_areg_glb<8>(xt, myrow, 128, 0, af, half);
    f32x16 accE[6];
#pragma unroll
    for (int c = 0; c < 6; ++c) {
      PH_BEGIN();
      accE[c] = zero16();
      mma_chunkW<8>(Wbuf[bufc], af, &accE[c], c31, half);
      PH_END();
    }
    ln_gelu_store32(accE, ebt, egt, ebbt, A, c31, half);
#pragma unroll
    for (int c = 0; c < 6; ++c) {
      PH_BEGIN();
      mma_chunkAW(A, Wbuf[bufc], &accF[c], c31, half);
      PH_END();
    }
    ln_gelu_store32(accF, fb, fg, fbb, A, c31, half);
  }

  // ===== 3 resonance layers =====
  for (int i = 0; i < 3; ++i) {
    {
      short8 afq[12];
      load_areg_lds(A, afq, c31, half);
      f32x16 accQ[6];
#pragma unroll
      for (int c = 0; c < 6; ++c) {
        PH_BEGIN();
        accQ[c] = zero16();
        mma_chunkW<12>(Wbuf[bufc], afq, &accQ[c], c31, half);
        PH_END();
      }
      bias_store32(accQ, rbq + i * 192, A, c31, half);
    }
    // attention: K/V directly from global (L1/L2-resident), per-wave rows
    {
      const ushort_t* kvl = kvf + i * 9216;
      const float scale = 0.144337567297406441f;  // 1/sqrt(48)
#pragma unroll
      for (int h = 0; h < 4; ++h) {
        f32x16 s = zero16();
#pragma unroll
        for (int ks = 0; ks < 3; ++ks) {
          int slot = h * 6 + ks * 2 + half;
          short8 a = *(const short8*)(A + c31 * 192 + ((slot ^ (c31 & 7)) << 3));
          short8 b = *(const short8*)(kvl + h * 1536 + c31 * 48 + ks * 16 + half * 8);
          s = MFMA32(a, b, s);
        }
#pragma unroll
        for (int r = 0; r < 16; ++r) {
          float v = s[r] * scale;
          float mx = v;
          mx = fmaxf(mx, __shfl_xor(mx, 1, 64));
          mx = fmaxf(mx, __shfl_xor(mx, 2, 64));
          mx = fmaxf(mx, __shfl_xor(mx, 4, 64));
          mx = fmaxf(mx, __shfl_xor(mx, 8, 64));
          float e = exp2f((v - mx) * 1.44269504f);
          float sm = e;
          sm += __shfl_xor(sm, 1, 64);
          sm += __shfl_xor(sm, 2, 64);
          sm += __shfl_xor(sm, 4, 64);
          sm += __shfl_xor(sm, 8, 64);
          if (c31 < 16) {
            int row = (r & 3) + 8 * (r >> 2) + 4 * half;
            Pw[row * 16 + c31] = f2bu(e * fastrcp(sm));
          }
        }
        short8 pa = *(const short8*)(Pw + c31 * 16 + half * 8);
#pragma unroll
        for (int t = 0; t < 2; ++t) {
          int d = t * 32 + c31;
          short8 vb;
#pragma unroll
          for (int j = 0; j < 8; ++j) vb[j] = 0;
          if (d < 48) vb = *(const short8*)(kvl + 6144 + h * 768 + d * 16 + half * 8);
          f32x16 o = MFMA32(pa, vb, zero16());
          if (d < 48) {
            int col = h * 48 + d;
#pragma unroll
            for (int r = 0; r < 16; ++r) {
              int row = (r & 3) + 8 * (r >> 2) + 4 * half;
              A[row * 192 + (((col >> 3) ^ (row & 7)) << 3) + (col & 7)] = f2bu(o[r]);
            }
          }
        }
      }
    }
    {
      short8 afo[12];
      load_areg_lds(A, afo, c31, half);
      f32x16 accO[6];
#pragma unroll
      for (int c = 0; c < 6; ++c) {
        PH_BEGIN();
        accO[c] = zero16();
        mma_chunkW<12>(Wbuf[bufc], afo, &accO[c], c31, half);
        PH_END();
      }
      bias_store32(accO, rbo + i * 192, A, c31, half);
    }
  }

  // ===== SOFM: argmax_g (f.g - ||g||^2/2) -> histogram =====
  {
    short8 afs[12];
    load_areg_lds(A, afs, c31, half);
    float bv[16]; int bi[16];
#pragma unroll
    for (int c = 0; c < 2; ++c) {
      PH_BEGIN();
      f32x16 s = zero16();
      mma_chunkW<12>(Wbuf[bufc], afs, &s, c31, half);
      float cl = c_l[c * 32 + c31];
#pragma unroll
      for (int r = 0; r < 16; ++r) {
        float v = s[r] - cl;
        if (c == 0) { bv[r] = v; bi[r] = c31; }
        else if (v > bv[r]) { bv[r] = v; bi[r] = 32 + c31; }
      }
      PH_END();
    }
#pragma unroll
    for (int r = 0; r < 16; ++r) {
#pragma unroll
      for (int off = 1; off < 32; off <<= 1) {
        float ov = __shfl_xor(bv[r], off, 64);
        int oi = __shfl_xor(bi[r], off, 64);
        bool take = (ov > bv[r]) || (ov == bv[r] && oi < bi[r]);
        bv[r] = take ? ov : bv[r];
        bi[r] = take ? oi : bi[r];
      }
    }
    if (c31 == 0) {
#pragma unroll
      for (int r = 0; r < 16; ++r) atomicAdd(&hist[bi[r]], 1u);
    }
  }
  __syncthreads();
  if (tid < 64 && hist[tid]) atomicAdd(&counts[tid], hist[tid]);
#undef PH_BEGIN
#undef PH_END
}

// ---------------- finisher ----------------
__global__ void arn_finish(const unsigned* __restrict__ counts, const float* __restrict__ gr,
                           const float* __restrict__ ow, const float* __restrict__ ob,
                           float* __restrict__ out) {
  __shared__ float pooled[192];
  __shared__ float cf[64];
  int t = threadIdx.x;
  if (t < 64) cf[t] = (float)counts[t];
  __syncthreads();
  float s = 0.f;
  for (int g = 0; g < 64; ++g) s += cf[g] * gr[g * 192 + t];
  pooled[t] = s * (1.0f / (float)B_TOTAL);
  __syncthreads();
  if (t < 6) {
    float o = ob[t];
    for (int j = 0; j < 192; ++j) o += pooled[j] * ow[j * 6 + t];
    out[t] = (t == 1) ? fmaxf(o, 0.f) : 1.f / (1.f + expf(-o));
  }
}

// ---------------- launch ----------------
extern "C" void kernel_launch(void* const* d_in, const int* in_sizes, int n_in,
                              void* d_out, int out_size, void* d_ws, size_t ws_size,
                              hipStream_t stream) {
  (void)in_sizes; (void)n_in; (void)out_size; (void)ws_size;
  const float* xv   = (const float*)d_in[0];
  const float* xa   = (const float*)d_in[1];
  const float* xt   = (const float*)d_in[2];
  const float* ewv  = (const float*)d_in[3];
  const float* ebv  = (const float*)d_in[4];
  const float* egv  = (const float*)d_in[5];
  const float* ebbv = (const float*)d_in[6];
  const float* ewa  = (const float*)d_in[7];
  const float* eba  = (const float*)d_in[8];
  const float* ega  = (const float*)d_in[9];
  const float* ebba = (const float*)d_in[10];
  const float* ewt  = (const float*)d_in[11];
  const float* ebt  = (const float*)d_in[12];
  const float* egt  = (const float*)d_in[13];
  const float* ebbt = (const float*)d_in[14];
  const float* fw   = (const float*)d_in[15];
  const float* fb   = (const float*)d_in[16];
  const float* fg   = (const float*)d_in[17];
  const float* fbb  = (const float*)d_in[18];
  const float* rwq  = (const float*)d_in[19];
  const float* rwk  = (const float*)d_in[20];
  const float* rwv  = (const float*)d_in[21];
  const float* rwo  = (const float*)d_in[22];
  const float* rbq  = (const float*)d_in[23];
  const float* rbk  = (const float*)d_in[24];
  const float* rbv  = (const float*)d_in[25];
  const float* rbo  = (const float*)d_in[26];
  const float* rmem = (const float*)d_in[27];
  const float* grid = (const float*)d_in[28];
  const float* ow   = (const float*)d_in[29];
  const float* ob   = (const float*)d_in[30];

  ushort_t* wsu = (ushort_t*)d_ws;
  ushort_t* kvf = wsu + OFF_KV;
  float* wsf = (float*)((char*)d_ws + F32_BYTE_OFF);
  float* ggn = wsf;
  unsigned* cnt = (unsigned*)(wsf + 64);

  prep_weights<<<dim3(256), dim3(256), 0, stream>>>(ewv, ewa, ewt, fw, rwq, rwo, grid, wsu);
  prep_kv<<<dim3(120), dim3(256), 0, stream>>>(rwk, rwv, rbk, rbv, rmem, grid, kvf, ggn, cnt);
  arn_main<<<dim3(1024), dim3(256), 0, stream>>>(xv, xa, xt, wsu, kvf, ggn, cnt,
      ebv, egv, ebbv, eba, ega, ebba, ebt, egt, ebbt, fb, fg, fbb, rbq, rbo);
  arn_finish<<<dim3(1), dim3(192), 0, stream>>>(cnt, grid, ow, ob, (float*)d_out);
}

// Round 6
// 660.228 us; speedup vs baseline: 1.2687x; 1.2687x over previous
//
#include <hip/hip_runtime.h>
#include <math.h>

typedef unsigned short ushort_t;
typedef __attribute__((ext_vector_type(8))) short short8;
typedef __attribute__((ext_vector_type(4))) float f32x4;

#define B_TOTAL 131072

// ws layout (ushort element offsets). W blobs are K-split chunk-major:
// chunk = [N rows][32 k] where storage (n, slot s, j) holds logical
// k = ck*32 + 8*(s ^ SWZ(n)) + j.  Staged linearly via global_load_lds.
#define SWZ(n) ((((n) & 3)) ^ (((n) >> 2) & 3))
#define OFF_VIB 0        // 2 chunks  [192][32] = 12288
#define OFF_ACO 12288    // 8 chunks             = 49152
#define OFF_TMP 61440    // 4 chunks             = 24576
#define OFF_FUS 86016    // 18 chunks            = 110592
#define OFF_WQ 196608    // 18 chunks (layer-major)
#define OFF_WO 307200    // 18 chunks
#define OFF_GRID 417792  // 6 chunks [64][32]    = 12288
#define OFF_KV 430080    // 3 layers x 10240: Kb[4h][16s][64k] + Vt[4h][48d][32s]
#define F32_BYTE_OFF 921600

__device__ __forceinline__ ushort_t f2bu(float f) {
  union { float f; unsigned u; } c; c.f = f;
  unsigned u = c.u;
  unsigned r = (u + 0x7fffu + ((u >> 16) & 1u)) >> 16;  // RTNE
  return (ushort_t)r;
}
__device__ __forceinline__ float fastrcp(float x) { return __builtin_amdgcn_rcpf(x); }
__device__ __forceinline__ float gelu_fast(float x) {
  float u = 0.7978845608f * x * (1.0f + 0.044715f * x * x);
  float E = exp2f(2.88539008f * u);
  float t = 1.0f - 2.0f * fastrcp(E + 1.0f);
  return 0.5f * x * (1.0f + t);
}
#define MFMA16(a, b, c) __builtin_amdgcn_mfma_f32_16x16x32_bf16(a, b, c, 0, 0, 0)

__device__ __forceinline__ void gload16(const void* g, void* l) {
  __builtin_amdgcn_global_load_lds((const __attribute__((address_space(1))) void*)g,
                                   (__attribute__((address_space(3))) void*)l, 16, 0, 0);
}

// ---------------- prep: weights -> K-split swizzled chunks ----------------
__global__ void prep_weights(const float* __restrict__ ev, const float* __restrict__ ea,
                             const float* __restrict__ et, const float* __restrict__ fw,
                             const float* __restrict__ rwq, const float* __restrict__ rwo,
                             const float* __restrict__ gr, ushort_t* __restrict__ ws) {
  int tid = blockIdx.x * blockDim.x + threadIdx.x;
  int nth = gridDim.x * blockDim.x;
  // vib: 2 chunks [192][32]; src ev [64][192]
  for (int i = tid; i < 12288; i += nth) {
    int ck = i / 6144, rem = i % 6144, n = rem >> 5, s = (rem >> 3) & 3, j = i & 7;
    int k = ck * 32 + 8 * (s ^ SWZ(n)) + j;
    ws[OFF_VIB + i] = f2bu(ev[k * 192 + n]);
  }
  // aco: 8 chunks; src ea [256][192]
  for (int i = tid; i < 49152; i += nth) {
    int ck = i / 6144, rem = i % 6144, n = rem >> 5, s = (rem >> 3) & 3, j = i & 7;
    int k = ck * 32 + 8 * (s ^ SWZ(n)) + j;
    ws[OFF_ACO + i] = f2bu(ea[k * 192 + n]);
  }
  // tmp: 4 chunks; src et [128][192]
  for (int i = tid; i < 24576; i += nth) {
    int ck = i / 6144, rem = i % 6144, n = rem >> 5, s = (rem >> 3) & 3, j = i & 7;
    int k = ck * 32 + 8 * (s ^ SWZ(n)) + j;
    ws[OFF_TMP + i] = f2bu(et[k * 192 + n]);
  }
  // fus: 18 chunks; src fw [576][192]
  for (int i = tid; i < 110592; i += nth) {
    int ck = i / 6144, rem = i % 6144, n = rem >> 5, s = (rem >> 3) & 3, j = i & 7;
    int k = ck * 32 + 8 * (s ^ SWZ(n)) + j;
    ws[OFF_FUS + i] = f2bu(fw[k * 192 + n]);
  }
  // wq/wo: 18 chunks each, 6 per layer
  for (int i = tid; i < 110592; i += nth) {
    int ck = i / 6144, rem = i % 6144, n = rem >> 5, s = (rem >> 3) & 3, j = i & 7;
    int l = ck / 6;
    int k = (ck % 6) * 32 + 8 * (s ^ SWZ(n)) + j;
    ws[OFF_WQ + i] = f2bu(rwq[l * 36864 + k * 192 + n]);
    ws[OFF_WO + i] = f2bu(rwo[l * 36864 + k * 192 + n]);
  }
  // grid: 6 chunks [64][32]; src gr [64][192] (B[n=g][k=d])
  for (int i = tid; i < 12288; i += nth) {
    int ck = i / 2048, rem = i % 2048, n = rem >> 5, s = (rem >> 3) & 3, j = i & 7;
    int k = ck * 32 + 8 * (s ^ SWZ(n)) + j;
    ws[OFF_GRID + i] = f2bu(gr[n * 192 + k]);
  }
}

// ------- prep: K/V operand banks (plain layout, read from global) ---------
__global__ void prep_kv(const float* __restrict__ rwk, const float* __restrict__ rwv,
                        const float* __restrict__ rbk, const float* __restrict__ rbv,
                        const float* __restrict__ rmem, const float* __restrict__ gr,
                        ushort_t* __restrict__ kvf, float* __restrict__ ggn,
                        unsigned* __restrict__ cnt) {
  int tid = blockIdx.x * blockDim.x + threadIdx.x;
  int nth = gridDim.x * blockDim.x;
  // Kb[i][h][s(16)][k(64; k>=48 zero)]
  for (int idx = tid; idx < 12288; idx += nth) {
    int i = idx >> 12, r = idx & 4095, h = r >> 10, s = (r >> 6) & 15, k = r & 63;
    float val = 0.f;
    if (k < 48) {
      int d = h * 48 + k;
      const float* w = rwk + i * 36864;
      const float* mm = rmem + i * 3072 + s * 192;
      float acc = rbk[i * 192 + d];
      for (int kk = 0; kk < 192; ++kk) acc += mm[kk] * w[kk * 192 + d];
      val = acc;
    }
    kvf[i * 10240 + h * 1024 + s * 64 + k] = f2bu(val);
  }
  // Vt[i][h][d(48)][s(32; s>=16 zero)]
  for (int idx = tid; idx < 18432; idx += nth) {
    int i = idx / 6144, r = idx % 6144, h = r / 1536, q = r % 1536, d = q >> 5, s = q & 31;
    float val = 0.f;
    if (s < 16) {
      int dd = h * 48 + d;
      const float* w = rwv + i * 36864;
      const float* mm = rmem + i * 3072 + s * 192;
      float acc = rbv[i * 192 + dd];
      for (int kk = 0; kk < 192; ++kk) acc += mm[kk] * w[kk * 192 + dd];
      val = acc;
    }
    kvf[i * 10240 + 4096 + h * 1536 + d * 32 + s] = f2bu(val);
  }
  for (int g = tid; g < 64; g += nth) {
    const float* gp = gr + g * 192;
    float s = 0.f;
    for (int k = 0; k < 192; ++k) s += gp[k] * gp[k];
    ggn[g] = s;
    cnt[g] = 0u;
  }
}

// ---------------- main-kernel helpers ----------------
__device__ __forceinline__ void stage_to(ushort_t* dst, const ushort_t* src, int n16,
                                         int wave, int lane) {
  for (int j = 0; j < n16; ++j) {
    int seg = (wave * n16 + j) << 9;  // 512 ushorts = 1KB per wave-issue
    gload16(src + seg + lane * 8, dst + seg);
  }
}

// consumption-order phase table
__device__ __forceinline__ const ushort_t* chunk_ptr(const ushort_t* wsu, int g, int* n16) {
  if (g < 2)            { *n16 = 3; return wsu + OFF_VIB + g * 6144; }
  g -= 2;  if (g < 6)   { *n16 = 3; return wsu + OFF_FUS + g * 6144; }
  g -= 6;  if (g < 8)   { *n16 = 3; return wsu + OFF_ACO + g * 6144; }
  g -= 8;  if (g < 6)   { *n16 = 3; return wsu + OFF_FUS + 36864 + g * 6144; }
  g -= 6;  if (g < 4)   { *n16 = 3; return wsu + OFF_TMP + g * 6144; }
  g -= 4;  if (g < 6)   { *n16 = 3; return wsu + OFF_FUS + 73728 + g * 6144; }
  g -= 6;  if (g < 36)  { int l = g / 12, r2 = g - l * 12;
    *n16 = 3;
    return (r2 < 6) ? (wsu + OFF_WQ + l * 36864 + r2 * 6144)
                    : (wsu + OFF_WO + l * 36864 + (r2 - 6) * 6144); }
  g -= 36; if (g < 6)   { *n16 = 1; return wsu + OFF_GRID + g * 2048; }
  *n16 = 0; return wsu;
}

__device__ __forceinline__ void phase_begin(const ushort_t* wsu, ushort_t (*Wb)[6144],
                                            int gph, int wave, int lane) {
  __syncthreads();
  int n16; const ushort_t* ns = chunk_ptr(wsu, gph + 1, &n16);
  if (n16) stage_to(&Wb[(gph + 1) & 1][0], ns, n16, wave, lane);
}

__device__ __forceinline__ short8 cvt8(float4 a, float4 b) {
  short8 v;
  v[0] = (short)f2bu(a.x); v[1] = (short)f2bu(a.y); v[2] = (short)f2bu(a.z); v[3] = (short)f2bu(a.w);
  v[4] = (short)f2bu(b.x); v[5] = (short)f2bu(b.y); v[6] = (short)f2bu(b.z); v[7] = (short)f2bu(b.w);
  return v;
}

// encoder GEMM: A streamed from global (fp32) with 1-phase register pipeline
template<int NPH>
__device__ __forceinline__ void enc_gemm(const float* __restrict__ x, int row0, int row1,
    const ushort_t* wsu, ushort_t (*Wb)[6144], int* gph, f32x4* accE,
    int wc0, int m, int gq, int wave, int lane) {
  const int KF = NPH * 32;
  float4 ca0 = *(const float4*)(x + (size_t)row0 * KF + gq * 8);
  float4 ca1 = *(const float4*)(x + (size_t)row0 * KF + gq * 8 + 4);
  float4 cb0 = *(const float4*)(x + (size_t)row1 * KF + gq * 8);
  float4 cb1 = *(const float4*)(x + (size_t)row1 * KF + gq * 8 + 4);
#pragma unroll
  for (int ph = 0; ph < NPH; ++ph) {
    phase_begin(wsu, Wb, *gph, wave, lane);
    const ushort_t* Wc = &Wb[*gph & 1][0];
    short8 a0 = cvt8(ca0, ca1);
    short8 a1 = cvt8(cb0, cb1);
    if (ph + 1 < NPH) {
      int ko = (ph + 1) * 32 + gq * 8;
      ca0 = *(const float4*)(x + (size_t)row0 * KF + ko);
      ca1 = *(const float4*)(x + (size_t)row0 * KF + ko + 4);
      cb0 = *(const float4*)(x + (size_t)row1 * KF + ko);
      cb1 = *(const float4*)(x + (size_t)row1 * KF + ko + 4);
    }
#pragma unroll
    for (int t = 0; t < 6; ++t) {
      int n = wc0 + t * 16 + m;
      short8 b = *(const short8*)(Wc + n * 32 + ((gq ^ SWZ(n)) << 3));
      accE[t]     = MFMA16(a0, b, accE[t]);
      accE[6 + t] = MFMA16(a1, b, accE[6 + t]);
    }
    ++*gph;
  }
}

// GEMM with A from the swizzled activation panel (6 phases, K=192)
__device__ __forceinline__ void lds_gemm(const ushort_t* Ab, const ushort_t* wsu,
    ushort_t (*Wb)[6144], int* gph, f32x4* acc, int wr0, int wc0, int m, int gq,
    int wave, int lane) {
#pragma unroll
  for (int ph = 0; ph < 6; ++ph) {
    phase_begin(wsu, Wb, *gph, wave, lane);
    const ushort_t* Wc = &Wb[*gph & 1][0];
    int r0 = wr0 + m, r1 = wr0 + 16 + m;
    short8 a0 = *(const short8*)(Ab + r0 * 192 + (((ph * 4 + gq) ^ (r0 & 7)) << 3));
    short8 a1 = *(const short8*)(Ab + r1 * 192 + (((ph * 4 + gq) ^ (r1 & 7)) << 3));
#pragma unroll
    for (int t = 0; t < 6; ++t) {
      int n = wc0 + t * 16 + m;
      short8 b = *(const short8*)(Wc + n * 32 + ((gq ^ SWZ(n)) << 3));
      acc[t]     = MFMA16(a0, b, acc[t]);
      acc[6 + t] = MFMA16(a1, b, acc[6 + t]);
    }
    ++*gph;
  }
}

// LN(+GELU) epilogue, col-split: cross-wave stats via 1KB scratch
__device__ __forceinline__ void ln_gelu_cs(f32x4* acc, const float* __restrict__ bias,
    const float* __restrict__ gam, const float* __restrict__ bet,
    ushort_t* __restrict__ Ab, float2 (*scr)[2], int wr0, int wc0, int colh,
    int m, int gq) {
#pragma unroll
  for (int t = 0; t < 12; ++t) {
    float bv = bias[wc0 + (t % 6) * 16 + m];
#pragma unroll
    for (int j = 0; j < 4; ++j) acc[t][j] += bv;
  }
#pragma unroll
  for (int mt = 0; mt < 2; ++mt)
#pragma unroll
    for (int j = 0; j < 4; ++j) {
      float s = 0.f, q = 0.f;
#pragma unroll
      for (int t = 0; t < 6; ++t) { float v = acc[mt * 6 + t][j]; s += v; q += v * v; }
#pragma unroll
      for (int off = 1; off < 16; off <<= 1) {
        s += __shfl_xor(s, off, 64);
        q += __shfl_xor(q, off, 64);
      }
      if (m == 0) scr[wr0 + mt * 16 + gq * 4 + j][colh] = (float2){s, q};
    }
  __syncthreads();
#pragma unroll
  for (int mt = 0; mt < 2; ++mt)
#pragma unroll
    for (int j = 0; j < 4; ++j) {
      int row = wr0 + mt * 16 + gq * 4 + j;
      float2 h0 = scr[row][0], h1 = scr[row][1];
      float mean = (h0.x + h1.x) * (1.0f / 192.0f);
      float var = (h0.y + h1.y) * (1.0f / 192.0f) - mean * mean;
      float rstd = rsqrtf(var + 1e-5f);
#pragma unroll
      for (int t = 0; t < 6; ++t) {
        int col = wc0 + t * 16 + m;
        float y = (acc[mt * 6 + t][j] - mean) * rstd * gam[col] + bet[col];
        Ab[row * 192 + ((((col >> 3) ^ (row & 7))) << 3) + (col & 7)] = f2bu(gelu_fast(y));
      }
    }
}

__device__ __forceinline__ void bias_store_cs(f32x4* acc, const float* __restrict__ bias,
    ushort_t* __restrict__ Ab, int wr0, int wc0, int m, int gq) {
#pragma unroll
  for (int mt = 0; mt < 2; ++mt)
#pragma unroll
    for (int t = 0; t < 6; ++t) {
      int col = wc0 + t * 16 + m;
      float bv = bias[col];
#pragma unroll
      for (int j = 0; j < 4; ++j) {
        int row = wr0 + mt * 16 + gq * 4 + j;
        Ab[row * 192 + ((((col >> 3) ^ (row & 7))) << 3) + (col & 7)] =
            f2bu(acc[mt * 6 + t][j] + bv);
      }
    }
}

// ---------------- main fused kernel ----------------
__global__ __launch_bounds__(256, 3) void arn_main(
    const float* __restrict__ xv, const float* __restrict__ xa, const float* __restrict__ xt,
    const ushort_t* __restrict__ wsu, const ushort_t* __restrict__ kvf,
    const float* __restrict__ ggn, unsigned* __restrict__ counts,
    const float* __restrict__ ebv, const float* __restrict__ egv, const float* __restrict__ ebbv,
    const float* __restrict__ eba, const float* __restrict__ ega, const float* __restrict__ ebba,
    const float* __restrict__ ebt, const float* __restrict__ egt, const float* __restrict__ ebbt,
    const float* __restrict__ fb, const float* __restrict__ fg, const float* __restrict__ fbb,
    const float* __restrict__ rbq, const float* __restrict__ rbo) {
  __shared__ __align__(16) ushort_t Abuf[64 * 192 + 64];  // swizzled activations + zero pad
  __shared__ __align__(16) ushort_t Wbuf[2][6144];        // double-buffered W chunks
  __shared__ float2 lnscr[64][2];
  __shared__ float c_l[64];
  __shared__ unsigned hist[64];

  const int tid = threadIdx.x, lane = tid & 63, wave = tid >> 6;
  const int m = lane & 15, gq = lane >> 4;
  const int wr0 = (wave & 1) * 32;       // GEMM row half
  const int wc0 = (wave >> 1) * 96;      // GEMM col half
  const int colh = wave >> 1;
  const int aw0 = wave * 16;             // attention row base
  const int growbase = blockIdx.x * 64;

  if (tid < 64) { hist[tid] = 0u; c_l[tid] = 0.5f * ggn[tid]; Abuf[12288 + tid] = 0; }

  int gph = 0;
  { int n16; const ushort_t* s0 = chunk_ptr(wsu, 0, &n16); stage_to(&Wbuf[0][0], s0, n16, wave, lane); }

  const int row0 = growbase + wr0 + m, row1 = row0 + 16;
  f32x4 accF[12];
#pragma unroll
  for (int t = 0; t < 12; ++t) accF[t] = (f32x4){0.f, 0.f, 0.f, 0.f};

  // ===== vib encoder + fus part 0 =====
  {
    f32x4 accE[12];
#pragma unroll
    for (int t = 0; t < 12; ++t) accE[t] = (f32x4){0.f, 0.f, 0.f, 0.f};
    enc_gemm<2>(xv, row0, row1, wsu, Wbuf, &gph, accE, wc0, m, gq, wave, lane);
    ln_gelu_cs(accE, ebv, egv, ebbv, Abuf, lnscr, wr0, wc0, colh, m, gq);
  }
  lds_gemm(Abuf, wsu, Wbuf, &gph, accF, wr0, wc0, m, gq, wave, lane);

  // ===== aco encoder + fus part 1 =====
  {
    f32x4 accE[12];
#pragma unroll
    for (int t = 0; t < 12; ++t) accE[t] = (f32x4){0.f, 0.f, 0.f, 0.f};
    enc_gemm<8>(xa, row0, row1, wsu, Wbuf, &gph, accE, wc0, m, gq, wave, lane);
    ln_gelu_cs(accE, eba, ega, ebba, Abuf, lnscr, wr0, wc0, colh, m, gq);
  }
  lds_gemm(Abuf, wsu, Wbuf, &gph, accF, wr0, wc0, m, gq, wave, lane);

  // ===== tmp encoder + fus part 2 + fusion LN =====
  {
    f32x4 accE[12];
#pragma unroll
    for (int t = 0; t < 12; ++t) accE[t] = (f32x4){0.f, 0.f, 0.f, 0.f};
    enc_gemm<4>(xt, row0, row1, wsu, Wbuf, &gph, accE, wc0, m, gq, wave, lane);
    ln_gelu_cs(accE, ebt, egt, ebbt, Abuf, lnscr, wr0, wc0, colh, m, gq);
  }
  lds_gemm(Abuf, wsu, Wbuf, &gph, accF, wr0, wc0, m, gq, wave, lane);
  ln_gelu_cs(accF, fb, fg, fbb, Abuf, lnscr, wr0, wc0, colh, m, gq);

  // ===== 3 resonance layers =====
  for (int i = 0; i < 3; ++i) {
    {
      f32x4 accQ[12];
#pragma unroll
      for (int t = 0; t < 12; ++t) accQ[t] = (f32x4){0.f, 0.f, 0.f, 0.f};
      lds_gemm(Abuf, wsu, Wbuf, &gph, accQ, wr0, wc0, m, gq, wave, lane);
      bias_store_cs(accQ, rbq + i * 192, Abuf, wr0, wc0, m, gq);
    }
    __syncthreads();  // Q visible to all waves; P-buffer (Wbuf[1]) free
    {
      const ushort_t* kvl = kvf + i * 10240;
      ushort_t* Pw = &Wbuf[1][0] + wave * 512;  // [16 rows][32 slots]
      // zero pad slots 16..31 (8B per lane)
      *(uint2*)(Pw + (lane >> 2) * 32 + 16 + (lane & 3) * 4) = (uint2){0u, 0u};
      const float scale = 0.144337567297406441f;  // 1/sqrt(48)
#pragma unroll
      for (int h = 0; h < 4; ++h) {
        f32x4 s4 = (f32x4){0.f, 0.f, 0.f, 0.f};
#pragma unroll
        for (int ks = 0; ks < 2; ++ks) {
          int kg = h * 6 + ks * 4 + gq;
          int r = aw0 + m;
          short8 a = *(const short8*)(Abuf + r * 192 + ((kg ^ (r & 7)) << 3));
          short8 b = *(const short8*)(kvl + h * 1024 + m * 64 + ks * 32 + gq * 8);
          s4 = MFMA16(a, b, s4);
        }
#pragma unroll
        for (int j = 0; j < 4; ++j) {
          float v = s4[j] * scale;
          float mx = v;
          mx = fmaxf(mx, __shfl_xor(mx, 1, 64));
          mx = fmaxf(mx, __shfl_xor(mx, 2, 64));
          mx = fmaxf(mx, __shfl_xor(mx, 4, 64));
          mx = fmaxf(mx, __shfl_xor(mx, 8, 64));
          float e = exp2f((v - mx) * 1.44269504f);
          float sm = e;
          sm += __shfl_xor(sm, 1, 64);
          sm += __shfl_xor(sm, 2, 64);
          sm += __shfl_xor(sm, 4, 64);
          sm += __shfl_xor(sm, 8, 64);
          Pw[(gq * 4 + j) * 32 + m] = f2bu(e * fastrcp(sm));
        }
        short8 pa = *(const short8*)(Pw + m * 32 + gq * 8);
#pragma unroll
        for (int t = 0; t < 3; ++t) {
          short8 vb = *(const short8*)(kvl + 4096 + h * 1536 + (t * 16 + m) * 32 + gq * 8);
          f32x4 o4 = MFMA16(pa, vb, ((f32x4){0.f, 0.f, 0.f, 0.f}));
          int col = h * 48 + t * 16 + m;
#pragma unroll
          for (int j = 0; j < 4; ++j) {
            int row = aw0 + gq * 4 + j;
            Abuf[row * 192 + ((((col >> 3) ^ (row & 7))) << 3) + (col & 7)] = f2bu(o4[j]);
          }
        }
      }
    }
    {
      f32x4 accO[12];
#pragma unroll
      for (int t = 0; t < 12; ++t) accO[t] = (f32x4){0.f, 0.f, 0.f, 0.f};
      lds_gemm(Abuf, wsu, Wbuf, &gph, accO, wr0, wc0, m, gq, wave, lane);
      bias_store_cs(accO, rbo + i * 192, Abuf, wr0, wc0, m, gq);
    }
  }

  // ===== SOFM: argmax_g (f.g - ||g||^2/2) -> histogram =====
  {
    f32x4 accS[8];
#pragma unroll
    for (int t = 0; t < 8; ++t) accS[t] = (f32x4){0.f, 0.f, 0.f, 0.f};
#pragma unroll
    for (int ph = 0; ph < 6; ++ph) {
      phase_begin(wsu, Wbuf, gph, wave, lane);
      const ushort_t* Wc = &Wbuf[gph & 1][0];
      int r0 = wr0 + m, r1 = wr0 + 16 + m;
      short8 a0 = *(const short8*)(Abuf + r0 * 192 + (((ph * 4 + gq) ^ (r0 & 7)) << 3));
      short8 a1 = *(const short8*)(Abuf + r1 * 192 + (((ph * 4 + gq) ^ (r1 & 7)) << 3));
#pragma unroll
      for (int nt = 0; nt < 4; ++nt) {
        int n = nt * 16 + m;
        short8 b = *(const short8*)(Wc + n * 32 + ((gq ^ SWZ(n)) << 3));
        accS[nt]     = MFMA16(a0, b, accS[nt]);
        accS[4 + nt] = MFMA16(a1, b, accS[4 + nt]);
      }
      ++gph;
    }
#pragma unroll
    for (int mt = 0; mt < 2; ++mt)
#pragma unroll
      for (int j = 0; j < 4; ++j) {
        float bv = -3.0e38f; int bi = 0;
#pragma unroll
        for (int nt = 0; nt < 4; ++nt) {
          int g = nt * 16 + m;
          float v = accS[mt * 4 + nt][j] - c_l[g];
          bool take = (v > bv);
          bv = take ? v : bv; bi = take ? g : bi;
        }
#pragma unroll
        for (int off = 1; off < 16; off <<= 1) {
          float ov = __shfl_xor(bv, off, 64);
          int oi = __shfl_xor(bi, off, 64);
          bool take = (ov > bv) || (ov == bv && oi < bi);
          bv = take ? ov : bv; bi = take ? oi : bi;
        }
        // FIX (R5 bug): both col-half waves compute the same rows' argmax;
        // only the colh==0 wave may contribute, else every row is counted twice.
        if (m == 0 && colh == 0) atomicAdd(&hist[bi], 1u);
      }
  }
  __syncthreads();
  if (tid < 64 && hist[tid]) atomicAdd(&counts[tid], hist[tid]);
}

// ---------------- finisher ----------------
__global__ void arn_finish(const unsigned* __restrict__ counts, const float* __restrict__ gr,
                           const float* __restrict__ ow, const float* __restrict__ ob,
                           float* __restrict__ out) {
  __shared__ float pooled[192];
  __shared__ float cf[64];
  int t = threadIdx.x;
  if (t < 64) cf[t] = (float)counts[t];
  __syncthreads();
  float s = 0.f;
  for (int g = 0; g < 64; ++g) s += cf[g] * gr[g * 192 + t];
  pooled[t] = s * (1.0f / (float)B_TOTAL);
  __syncthreads();
  if (t < 6) {
    float o = ob[t];
    for (int j = 0; j < 192; ++j) o += pooled[j] * ow[j * 6 + t];
    out[t] = (t == 1) ? fmaxf(o, 0.f) : 1.f / (1.f + expf(-o));
  }
}

// ---------------- launch ----------------
extern "C" void kernel_launch(void* const* d_in, const int* in_sizes, int n_in,
                              void* d_out, int out_size, void* d_ws, size_t ws_size,
                              hipStream_t stream) {
  (void)in_sizes; (void)n_in; (void)out_size; (void)ws_size;
  const float* xv   = (const float*)d_in[0];
  const float* xa   = (const float*)d_in[1];
  const float* xt   = (const float*)d_in[2];
  const float* ewv  = (const float*)d_in[3];
  const float* ebv  = (const float*)d_in[4];
  const float* egv  = (const float*)d_in[5];
  const float* ebbv = (const float*)d_in[6];
  const float* ewa  = (const float*)d_in[7];
  const float* eba  = (const float*)d_in[8];
  const float* ega  = (const float*)d_in[9];
  const float* ebba = (const float*)d_in[10];
  const float* ewt  = (const float*)d_in[11];
  const float* ebt  = (const float*)d_in[12];
  const float* egt  = (const float*)d_in[13];
  const float* ebbt = (const float*)d_in[14];
  const float* fw   = (const float*)d_in[15];
  const float* fb   = (const float*)d_in[16];
  const float* fg   = (const float*)d_in[17];
  const float* fbb  = (const float*)d_in[18];
  const float* rwq  = (const float*)d_in[19];
  const float* rwk  = (const float*)d_in[20];
  const float* rwv  = (const float*)d_in[21];
  const float* rwo  = (const float*)d_in[22];
  const float* rbq  = (const float*)d_in[23];
  const float* rbk  = (const float*)d_in[24];
  const float* rbv  = (const float*)d_in[25];
  const float* rbo  = (const float*)d_in[26];
  const float* rmem = (const float*)d_in[27];
  const float* grid = (const float*)d_in[28];
  const float* ow   = (const float*)d_in[29];
  const float* ob   = (const float*)d_in[30];

  ushort_t* wsu = (ushort_t*)d_ws;
  ushort_t* kvf = wsu + OFF_KV;
  float* wsf = (float*)((char*)d_ws + F32_BYTE_OFF);
  float* ggn = wsf;
  unsigned* cnt = (unsigned*)(wsf + 64);

  prep_weights<<<dim3(256), dim3(256), 0, stream>>>(ewv, ewa, ewt, fw, rwq, rwo, grid, wsu);
  prep_kv<<<dim3(120), dim3(256), 0, stream>>>(rwk, rwv, rbk, rbv, rmem, grid, kvf, ggn, cnt);
  arn_main<<<dim3(2048), dim3(256), 0, stream>>>(xv, xa, xt, wsu, kvf, ggn, cnt,
      ebv, egv, ebbv, eba, ega, ebba, ebt, egt, ebbt, fb, fg, fbb, rbq, rbo);
  arn_finish<<<dim3(1), dim3(192), 0, stream>>>(cnt, grid, ow, ob, (float*)d_out);
}

// Round 7
// 494.077 us; speedup vs baseline: 1.6953x; 1.3363x over previous
//
#include <hip/hip_runtime.h>
#include <math.h>

typedef unsigned short ushort_t;
typedef __attribute__((ext_vector_type(8))) short short8;
typedef __attribute__((ext_vector_type(4))) float f32x4;

#define B_TOTAL 131072

// ws layout (ushort element offsets). W blobs are K-split chunk-major:
// chunk = [N rows][32 k] where storage (n, slot s, j) holds logical
// k = ck*32 + 8*(s ^ SWZ(n)) + j.  Staged linearly via global_load_lds.
#define SWZ(n) ((((n) & 3)) ^ (((n) >> 2) & 3))
#define OFF_VIB 0        // 2 chunks  [192][32] = 12288
#define OFF_ACO 12288    // 8 chunks             = 49152
#define OFF_TMP 61440    // 4 chunks             = 24576
#define OFF_FUS 86016    // 18 chunks            = 110592
#define OFF_WQ 196608    // 18 chunks (layer-major)
#define OFF_WO 307200    // 18 chunks
#define OFF_GRID 417792  // 6 chunks [64][32]    = 12288
#define OFF_KV 430080    // 3 layers x 10240: Kb[4h][16s][64k] + Vt[4h][48d][32s]
#define F32_BYTE_OFF 921600

__device__ __forceinline__ ushort_t f2bu(float f) {
  union { float f; unsigned u; } c; c.f = f;
  unsigned u = c.u;
  unsigned r = (u + 0x7fffu + ((u >> 16) & 1u)) >> 16;  // RTNE
  return (ushort_t)r;
}
__device__ __forceinline__ float fastrcp(float x) { return __builtin_amdgcn_rcpf(x); }
__device__ __forceinline__ float gelu_fast(float x) {
  float u = 0.7978845608f * x * (1.0f + 0.044715f * x * x);
  float E = exp2f(2.88539008f * u);
  float t = 1.0f - 2.0f * fastrcp(E + 1.0f);
  return 0.5f * x * (1.0f + t);
}
#define MFMA16(a, b, c) __builtin_amdgcn_mfma_f32_16x16x32_bf16(a, b, c, 0, 0, 0)

__device__ __forceinline__ void gload16(const void* g, void* l) {
  __builtin_amdgcn_global_load_lds((const __attribute__((address_space(1))) void*)g,
                                   (__attribute__((address_space(3))) void*)l, 16, 0, 0);
}

// ---------------- prep: weights -> K-split swizzled chunks ----------------
__global__ void prep_weights(const float* __restrict__ ev, const float* __restrict__ ea,
                             const float* __restrict__ et, const float* __restrict__ fw,
                             const float* __restrict__ rwq, const float* __restrict__ rwo,
                             const float* __restrict__ gr, ushort_t* __restrict__ ws) {
  int tid = blockIdx.x * blockDim.x + threadIdx.x;
  int nth = gridDim.x * blockDim.x;
  // vib: 2 chunks [192][32]; src ev [64][192]
  for (int i = tid; i < 12288; i += nth) {
    int ck = i / 6144, rem = i % 6144, n = rem >> 5, s = (rem >> 3) & 3, j = i & 7;
    int k = ck * 32 + 8 * (s ^ SWZ(n)) + j;
    ws[OFF_VIB + i] = f2bu(ev[k * 192 + n]);
  }
  // aco: 8 chunks; src ea [256][192]
  for (int i = tid; i < 49152; i += nth) {
    int ck = i / 6144, rem = i % 6144, n = rem >> 5, s = (rem >> 3) & 3, j = i & 7;
    int k = ck * 32 + 8 * (s ^ SWZ(n)) + j;
    ws[OFF_ACO + i] = f2bu(ea[k * 192 + n]);
  }
  // tmp: 4 chunks; src et [128][192]
  for (int i = tid; i < 24576; i += nth) {
    int ck = i / 6144, rem = i % 6144, n = rem >> 5, s = (rem >> 3) & 3, j = i & 7;
    int k = ck * 32 + 8 * (s ^ SWZ(n)) + j;
    ws[OFF_TMP + i] = f2bu(et[k * 192 + n]);
  }
  // fus: 18 chunks; src fw [576][192]
  for (int i = tid; i < 110592; i += nth) {
    int ck = i / 6144, rem = i % 6144, n = rem >> 5, s = (rem >> 3) & 3, j = i & 7;
    int k = ck * 32 + 8 * (s ^ SWZ(n)) + j;
    ws[OFF_FUS + i] = f2bu(fw[k * 192 + n]);
  }
  // wq/wo: 18 chunks each, 6 per layer
  for (int i = tid; i < 110592; i += nth) {
    int ck = i / 6144, rem = i % 6144, n = rem >> 5, s = (rem >> 3) & 3, j = i & 7;
    int l = ck / 6;
    int k = (ck % 6) * 32 + 8 * (s ^ SWZ(n)) + j;
    ws[OFF_WQ + i] = f2bu(rwq[l * 36864 + k * 192 + n]);
    ws[OFF_WO + i] = f2bu(rwo[l * 36864 + k * 192 + n]);
  }
  // grid: 6 chunks [64][32]; src gr [64][192] (B[n=g][k=d])
  for (int i = tid; i < 12288; i += nth) {
    int ck = i / 2048, rem = i % 2048, n = rem >> 5, s = (rem >> 3) & 3, j = i & 7;
    int k = ck * 32 + 8 * (s ^ SWZ(n)) + j;
    ws[OFF_GRID + i] = f2bu(gr[n * 192 + k]);
  }
}

// ------- prep: K/V operand banks (plain layout, read from global) ---------
__global__ void prep_kv(const float* __restrict__ rwk, const float* __restrict__ rwv,
                        const float* __restrict__ rbk, const float* __restrict__ rbv,
                        const float* __restrict__ rmem, const float* __restrict__ gr,
                        ushort_t* __restrict__ kvf, float* __restrict__ ggn,
                        unsigned* __restrict__ cnt) {
  int tid = blockIdx.x * blockDim.x + threadIdx.x;
  int nth = gridDim.x * blockDim.x;
  // Kb[i][h][s(16)][k(64; k>=48 zero)]
  for (int idx = tid; idx < 12288; idx += nth) {
    int i = idx >> 12, r = idx & 4095, h = r >> 10, s = (r >> 6) & 15, k = r & 63;
    float val = 0.f;
    if (k < 48) {
      int d = h * 48 + k;
      const float* w = rwk + i * 36864;
      const float* mm = rmem + i * 3072 + s * 192;
      float acc = rbk[i * 192 + d];
      for (int kk = 0; kk < 192; ++kk) acc += mm[kk] * w[kk * 192 + d];
      val = acc;
    }
    kvf[i * 10240 + h * 1024 + s * 64 + k] = f2bu(val);
  }
  // Vt[i][h][d(48)][s(32; s>=16 zero)]
  for (int idx = tid; idx < 18432; idx += nth) {
    int i = idx / 6144, r = idx % 6144, h = r / 1536, q = r % 1536, d = q >> 5, s = q & 31;
    float val = 0.f;
    if (s < 16) {
      int dd = h * 48 + d;
      const float* w = rwv + i * 36864;
      const float* mm = rmem + i * 3072 + s * 192;
      float acc = rbv[i * 192 + dd];
      for (int kk = 0; kk < 192; ++kk) acc += mm[kk] * w[kk * 192 + dd];
      val = acc;
    }
    kvf[i * 10240 + 4096 + h * 1536 + d * 32 + s] = f2bu(val);
  }
  for (int g = tid; g < 64; g += nth) {
    const float* gp = gr + g * 192;
    float s = 0.f;
    for (int k = 0; k < 192; ++k) s += gp[k] * gp[k];
    ggn[g] = s;
    cnt[g] = 0u;
  }
}

// ---------------- main-kernel helpers ----------------
__device__ __forceinline__ void stage_to(ushort_t* dst, const ushort_t* src, int n16,
                                         int wave, int lane) {
  for (int j = 0; j < n16; ++j) {
    int seg = (wave * n16 + j) << 9;  // 512 ushorts = 1KB per wave-issue
    gload16(src + seg + lane * 8, dst + seg);
  }
}

// consumption-order phase table
__device__ __forceinline__ const ushort_t* chunk_ptr(const ushort_t* wsu, int g, int* n16) {
  if (g < 2)            { *n16 = 3; return wsu + OFF_VIB + g * 6144; }
  g -= 2;  if (g < 6)   { *n16 = 3; return wsu + OFF_FUS + g * 6144; }
  g -= 6;  if (g < 8)   { *n16 = 3; return wsu + OFF_ACO + g * 6144; }
  g -= 8;  if (g < 6)   { *n16 = 3; return wsu + OFF_FUS + 36864 + g * 6144; }
  g -= 6;  if (g < 4)   { *n16 = 3; return wsu + OFF_TMP + g * 6144; }
  g -= 4;  if (g < 6)   { *n16 = 3; return wsu + OFF_FUS + 73728 + g * 6144; }
  g -= 6;  if (g < 36)  { int l = g / 12, r2 = g - l * 12;
    *n16 = 3;
    return (r2 < 6) ? (wsu + OFF_WQ + l * 36864 + r2 * 6144)
                    : (wsu + OFF_WO + l * 36864 + (r2 - 6) * 6144); }
  g -= 36; if (g < 6)   { *n16 = 1; return wsu + OFF_GRID + g * 2048; }
  *n16 = 0; return wsu;
}

__device__ __forceinline__ void phase_begin(const ushort_t* wsu, ushort_t (*Wb)[6144],
                                            int gph, int wave, int lane) {
  __syncthreads();
  int n16; const ushort_t* ns = chunk_ptr(wsu, gph + 1, &n16);
  if (n16) stage_to(&Wb[(gph + 1) & 1][0], ns, n16, wave, lane);
}

__device__ __forceinline__ short8 cvt8(float4 a, float4 b) {
  short8 v;
  v[0] = (short)f2bu(a.x); v[1] = (short)f2bu(a.y); v[2] = (short)f2bu(a.z); v[3] = (short)f2bu(a.w);
  v[4] = (short)f2bu(b.x); v[5] = (short)f2bu(b.y); v[6] = (short)f2bu(b.z); v[7] = (short)f2bu(b.w);
  return v;
}

// encoder GEMM: A streamed from global (fp32) with 1-phase register pipeline
template<int NPH>
__device__ __forceinline__ void enc_gemm(const float* __restrict__ x, int row0, int row1,
    const ushort_t* wsu, ushort_t (*Wb)[6144], int* gph, f32x4* accE,
    int wc0, int m, int gq, int wave, int lane) {
  const int KF = NPH * 32;
  float4 ca0 = *(const float4*)(x + (size_t)row0 * KF + gq * 8);
  float4 ca1 = *(const float4*)(x + (size_t)row0 * KF + gq * 8 + 4);
  float4 cb0 = *(const float4*)(x + (size_t)row1 * KF + gq * 8);
  float4 cb1 = *(const float4*)(x + (size_t)row1 * KF + gq * 8 + 4);
#pragma unroll
  for (int ph = 0; ph < NPH; ++ph) {
    phase_begin(wsu, Wb, *gph, wave, lane);
    const ushort_t* Wc = &Wb[*gph & 1][0];
    short8 a0 = cvt8(ca0, ca1);
    short8 a1 = cvt8(cb0, cb1);
    if (ph + 1 < NPH) {
      int ko = (ph + 1) * 32 + gq * 8;
      ca0 = *(const float4*)(x + (size_t)row0 * KF + ko);
      ca1 = *(const float4*)(x + (size_t)row0 * KF + ko + 4);
      cb0 = *(const float4*)(x + (size_t)row1 * KF + ko);
      cb1 = *(const float4*)(x + (size_t)row1 * KF + ko + 4);
    }
#pragma unroll
    for (int t = 0; t < 6; ++t) {
      int n = wc0 + t * 16 + m;
      short8 b = *(const short8*)(Wc + n * 32 + ((gq ^ SWZ(n)) << 3));
      accE[t]     = MFMA16(a0, b, accE[t]);
      accE[6 + t] = MFMA16(a1, b, accE[6 + t]);
    }
    ++*gph;
  }
}

// GEMM with A from the swizzled activation panel (6 phases, K=192)
__device__ __forceinline__ void lds_gemm(const ushort_t* Ab, const ushort_t* wsu,
    ushort_t (*Wb)[6144], int* gph, f32x4* acc, int wr0, int wc0, int m, int gq,
    int wave, int lane) {
#pragma unroll
  for (int ph = 0; ph < 6; ++ph) {
    phase_begin(wsu, Wb, gph ? *gph : *gph, wave, lane);
    const ushort_t* Wc = &Wb[*gph & 1][0];
    int r0 = wr0 + m, r1 = wr0 + 16 + m;
    short8 a0 = *(const short8*)(Ab + r0 * 192 + (((ph * 4 + gq) ^ (r0 & 7)) << 3));
    short8 a1 = *(const short8*)(Ab + r1 * 192 + (((ph * 4 + gq) ^ (r1 & 7)) << 3));
#pragma unroll
    for (int t = 0; t < 6; ++t) {
      int n = wc0 + t * 16 + m;
      short8 b = *(const short8*)(Wc + n * 32 + ((gq ^ SWZ(n)) << 3));
      acc[t]     = MFMA16(a0, b, acc[t]);
      acc[6 + t] = MFMA16(a1, b, acc[6 + t]);
    }
    ++*gph;
  }
}

// LN(+GELU) epilogue, col-split: cross-wave stats via 1KB scratch
__device__ __forceinline__ void ln_gelu_cs(f32x4* acc, const float* __restrict__ bias,
    const float* __restrict__ gam, const float* __restrict__ bet,
    ushort_t* __restrict__ Ab, float2 (*scr)[2], int wr0, int wc0, int colh,
    int m, int gq) {
#pragma unroll
  for (int t = 0; t < 12; ++t) {
    float bv = bias[wc0 + (t % 6) * 16 + m];
#pragma unroll
    for (int j = 0; j < 4; ++j) acc[t][j] += bv;
  }
#pragma unroll
  for (int mt = 0; mt < 2; ++mt)
#pragma unroll
    for (int j = 0; j < 4; ++j) {
      float s = 0.f, q = 0.f;
#pragma unroll
      for (int t = 0; t < 6; ++t) { float v = acc[mt * 6 + t][j]; s += v; q += v * v; }
#pragma unroll
      for (int off = 1; off < 16; off <<= 1) {
        s += __shfl_xor(s, off, 64);
        q += __shfl_xor(q, off, 64);
      }
      if (m == 0) scr[wr0 + mt * 16 + gq * 4 + j][colh] = (float2){s, q};
    }
  __syncthreads();
#pragma unroll
  for (int mt = 0; mt < 2; ++mt)
#pragma unroll
    for (int j = 0; j < 4; ++j) {
      int row = wr0 + mt * 16 + gq * 4 + j;
      float2 h0 = scr[row][0], h1 = scr[row][1];
      float mean = (h0.x + h1.x) * (1.0f / 192.0f);
      float var = (h0.y + h1.y) * (1.0f / 192.0f) - mean * mean;
      float rstd = rsqrtf(var + 1e-5f);
#pragma unroll
      for (int t = 0; t < 6; ++t) {
        int col = wc0 + t * 16 + m;
        float y = (acc[mt * 6 + t][j] - mean) * rstd * gam[col] + bet[col];
        Ab[row * 192 + ((((col >> 3) ^ (row & 7))) << 3) + (col & 7)] = f2bu(gelu_fast(y));
      }
    }
}

__device__ __forceinline__ void bias_store_cs(f32x4* acc, const float* __restrict__ bias,
    ushort_t* __restrict__ Ab, int wr0, int wc0, int m, int gq) {
#pragma unroll
  for (int mt = 0; mt < 2; ++mt)
#pragma unroll
    for (int t = 0; t < 6; ++t) {
      int col = wc0 + t * 16 + m;
      float bv = bias[col];
#pragma unroll
      for (int j = 0; j < 4; ++j) {
        int row = wr0 + mt * 16 + gq * 4 + j;
        Ab[row * 192 + ((((col >> 3) ^ (row & 7))) << 3) + (col & 7)] =
            f2bu(acc[mt * 6 + t][j] + bv);
      }
    }
}

// ---------------- main fused kernel ----------------
// R7: pin occupancy at 2 waves/EU -> 256-reg/wave budget (arch+acc); the
// accE+accF co-live set (96 acc regs) fits, eliminating R6's scratch spill
// (WRITE_SIZE 252 MB -> ~0).
__global__ __launch_bounds__(256) __attribute__((amdgpu_waves_per_eu(2, 2))) void arn_main(
    const float* __restrict__ xv, const float* __restrict__ xa, const float* __restrict__ xt,
    const ushort_t* __restrict__ wsu, const ushort_t* __restrict__ kvf,
    const float* __restrict__ ggn, unsigned* __restrict__ counts,
    const float* __restrict__ ebv, const float* __restrict__ egv, const float* __restrict__ ebbv,
    const float* __restrict__ eba, const float* __restrict__ ega, const float* __restrict__ ebba,
    const float* __restrict__ ebt, const float* __restrict__ egt, const float* __restrict__ ebbt,
    const float* __restrict__ fb, const float* __restrict__ fg, const float* __restrict__ fbb,
    const float* __restrict__ rbq, const float* __restrict__ rbo) {
  __shared__ __align__(16) ushort_t Abuf[64 * 192 + 64];  // swizzled activations + zero pad
  __shared__ __align__(16) ushort_t Wbuf[2][6144];        // double-buffered W chunks
  __shared__ float2 lnscr[64][2];
  __shared__ float c_l[64];
  __shared__ unsigned hist[64];

  const int tid = threadIdx.x, lane = tid & 63, wave = tid >> 6;
  const int m = lane & 15, gq = lane >> 4;
  const int wr0 = (wave & 1) * 32;       // GEMM row half
  const int wc0 = (wave >> 1) * 96;      // GEMM col half
  const int colh = wave >> 1;
  const int aw0 = wave * 16;             // attention row base
  const int growbase = blockIdx.x * 64;

  if (tid < 64) { hist[tid] = 0u; c_l[tid] = 0.5f * ggn[tid]; Abuf[12288 + tid] = 0; }

  int gph = 0;
  { int n16; const ushort_t* s0 = chunk_ptr(wsu, 0, &n16); stage_to(&Wbuf[0][0], s0, n16, wave, lane); }

  const int row0 = growbase + wr0 + m, row1 = row0 + 16;
  f32x4 accF[12];
#pragma unroll
  for (int t = 0; t < 12; ++t) accF[t] = (f32x4){0.f, 0.f, 0.f, 0.f};

  // ===== vib encoder + fus part 0 =====
  {
    f32x4 accE[12];
#pragma unroll
    for (int t = 0; t < 12; ++t) accE[t] = (f32x4){0.f, 0.f, 0.f, 0.f};
    enc_gemm<2>(xv, row0, row1, wsu, Wbuf, &gph, accE, wc0, m, gq, wave, lane);
    ln_gelu_cs(accE, ebv, egv, ebbv, Abuf, lnscr, wr0, wc0, colh, m, gq);
  }
  lds_gemm(Abuf, wsu, Wbuf, &gph, accF, wr0, wc0, m, gq, wave, lane);

  // ===== aco encoder + fus part 1 =====
  {
    f32x4 accE[12];
#pragma unroll
    for (int t = 0; t < 12; ++t) accE[t] = (f32x4){0.f, 0.f, 0.f, 0.f};
    enc_gemm<8>(xa, row0, row1, wsu, Wbuf, &gph, accE, wc0, m, gq, wave, lane);
    ln_gelu_cs(accE, eba, ega, ebba, Abuf, lnscr, wr0, wc0, colh, m, gq);
  }
  lds_gemm(Abuf, wsu, Wbuf, &gph, accF, wr0, wc0, m, gq, wave, lane);

  // ===== tmp encoder + fus part 2 + fusion LN =====
  {
    f32x4 accE[12];
#pragma unroll
    for (int t = 0; t < 12; ++t) accE[t] = (f32x4){0.f, 0.f, 0.f, 0.f};
    enc_gemm<4>(xt, row0, row1, wsu, Wbuf, &gph, accE, wc0, m, gq, wave, lane);
    ln_gelu_cs(accE, ebt, egt, ebbt, Abuf, lnscr, wr0, wc0, colh, m, gq);
  }
  lds_gemm(Abuf, wsu, Wbuf, &gph, accF, wr0, wc0, m, gq, wave, lane);
  ln_gelu_cs(accF, fb, fg, fbb, Abuf, lnscr, wr0, wc0, colh, m, gq);

  // ===== 3 resonance layers =====
  for (int i = 0; i < 3; ++i) {
    {
      f32x4 accQ[12];
#pragma unroll
      for (int t = 0; t < 12; ++t) accQ[t] = (f32x4){0.f, 0.f, 0.f, 0.f};
      lds_gemm(Abuf, wsu, Wbuf, &gph, accQ, wr0, wc0, m, gq, wave, lane);
      bias_store_cs(accQ, rbq + i * 192, Abuf, wr0, wc0, m, gq);
    }
    __syncthreads();  // Q visible to all waves; P-buffer (Wbuf[1]) free
    {
      const ushort_t* kvl = kvf + i * 10240;
      ushort_t* Pw = &Wbuf[1][0] + wave * 512;  // [16 rows][32 slots]
      // zero pad slots 16..31 (8B per lane)
      *(uint2*)(Pw + (lane >> 2) * 32 + 16 + (lane & 3) * 4) = (uint2){0u, 0u};
      const float scale = 0.144337567297406441f;  // 1/sqrt(48)
#pragma unroll
      for (int h = 0; h < 4; ++h) {
        f32x4 s4 = (f32x4){0.f, 0.f, 0.f, 0.f};
#pragma unroll
        for (int ks = 0; ks < 2; ++ks) {
          int kg = h * 6 + ks * 4 + gq;
          int r = aw0 + m;
          short8 a = *(const short8*)(Abuf + r * 192 + ((kg ^ (r & 7)) << 3));
          short8 b = *(const short8*)(kvl + h * 1024 + m * 64 + ks * 32 + gq * 8);
          s4 = MFMA16(a, b, s4);
        }
#pragma unroll
        for (int j = 0; j < 4; ++j) {
          float v = s4[j] * scale;
          float mx = v;
          mx = fmaxf(mx, __shfl_xor(mx, 1, 64));
          mx = fmaxf(mx, __shfl_xor(mx, 2, 64));
          mx = fmaxf(mx, __shfl_xor(mx, 4, 64));
          mx = fmaxf(mx, __shfl_xor(mx, 8, 64));
          float e = exp2f((v - mx) * 1.44269504f);
          float sm = e;
          sm += __shfl_xor(sm, 1, 64);
          sm += __shfl_xor(sm, 2, 64);
          sm += __shfl_xor(sm, 4, 64);
          sm += __shfl_xor(sm, 8, 64);
          Pw[(gq * 4 + j) * 32 + m] = f2bu(e * fastrcp(sm));
        }
        short8 pa = *(const short8*)(Pw + m * 32 + gq * 8);
#pragma unroll
        for (int t = 0; t < 3; ++t) {
          short8 vb = *(const short8*)(kvl + 4096 + h * 1536 + (t * 16 + m) * 32 + gq * 8);
          f32x4 o4 = MFMA16(pa, vb, ((f32x4){0.f, 0.f, 0.f, 0.f}));
          int col = h * 48 + t * 16 + m;
#pragma unroll
          for (int j = 0; j < 4; ++j) {
            int row = aw0 + gq * 4 + j;
            Abuf[row * 192 + ((((col >> 3) ^ (row & 7))) << 3) + (col & 7)] = f2bu(o4[j]);
          }
        }
      }
    }
    {
      f32x4 accO[12];
#pragma unroll
      for (int t = 0; t < 12; ++t) accO[t] = (f32x4){0.f, 0.f, 0.f, 0.f};
      lds_gemm(Abuf, wsu, Wbuf, &gph, accO, wr0, wc0, m, gq, wave, lane);
      bias_store_cs(accO, rbo + i * 192, Abuf, wr0, wc0, m, gq);
    }
  }

  // ===== SOFM: argmax_g (f.g - ||g||^2/2) -> histogram =====
  {
    f32x4 accS[8];
#pragma unroll
    for (int t = 0; t < 8; ++t) accS[t] = (f32x4){0.f, 0.f, 0.f, 0.f};
#pragma unroll
    for (int ph = 0; ph < 6; ++ph) {
      phase_begin(wsu, Wbuf, gph, wave, lane);
      const ushort_t* Wc = &Wbuf[gph & 1][0];
      int r0 = wr0 + m, r1 = wr0 + 16 + m;
      short8 a0 = *(const short8*)(Abuf + r0 * 192 + (((ph * 4 + gq) ^ (r0 & 7)) << 3));
      short8 a1 = *(const short8*)(Abuf + r1 * 192 + (((ph * 4 + gq) ^ (r1 & 7)) << 3));
#pragma unroll
      for (int nt = 0; nt < 4; ++nt) {
        int n = nt * 16 + m;
        short8 b = *(const short8*)(Wc + n * 32 + ((gq ^ SWZ(n)) << 3));
        accS[nt]     = MFMA16(a0, b, accS[nt]);
        accS[4 + nt] = MFMA16(a1, b, accS[4 + nt]);
      }
      ++gph;
    }
#pragma unroll
    for (int mt = 0; mt < 2; ++mt)
#pragma unroll
      for (int j = 0; j < 4; ++j) {
        float bv = -3.0e38f; int bi = 0;
#pragma unroll
        for (int nt = 0; nt < 4; ++nt) {
          int g = nt * 16 + m;
          float v = accS[mt * 4 + nt][j] - c_l[g];
          bool take = (v > bv);
          bv = take ? v : bv; bi = take ? g : bi;
        }
#pragma unroll
        for (int off = 1; off < 16; off <<= 1) {
          float ov = __shfl_xor(bv, off, 64);
          int oi = __shfl_xor(bi, off, 64);
          bool take = (ov > bv) || (ov == bv && oi < bi);
          bv = take ? ov : bv; bi = take ? oi : bi;
        }
        // both col-half waves compute the same rows' argmax; only colh==0 counts
        if (m == 0 && colh == 0) atomicAdd(&hist[bi], 1u);
      }
  }
  __syncthreads();
  if (tid < 64 && hist[tid]) atomicAdd(&counts[tid], hist[tid]);
}

// ---------------- finisher ----------------
__global__ void arn_finish(const unsigned* __restrict__ counts, const float* __restrict__ gr,
                           const float* __restrict__ ow, const float* __restrict__ ob,
                           float* __restrict__ out) {
  __shared__ float pooled[192];
  __shared__ float cf[64];
  int t = threadIdx.x;
  if (t < 64) cf[t] = (float)counts[t];
  __syncthreads();
  float s = 0.f;
  for (int g = 0; g < 64; ++g) s += cf[g] * gr[g * 192 + t];
  pooled[t] = s * (1.0f / (float)B_TOTAL);
  __syncthreads();
  if (t < 6) {
    float o = ob[t];
    for (int j = 0; j < 192; ++j) o += pooled[j] * ow[j * 6 + t];
    out[t] = (t == 1) ? fmaxf(o, 0.f) : 1.f / (1.f + expf(-o));
  }
}

// ---------------- launch ----------------
extern "C" void kernel_launch(void* const* d_in, const int* in_sizes, int n_in,
                              void* d_out, int out_size, void* d_ws, size_t ws_size,
                              hipStream_t stream) {
  (void)in_sizes; (void)n_in; (void)out_size; (void)ws_size;
  const float* xv   = (const float*)d_in[0];
  const float* xa   = (const float*)d_in[1];
  const float* xt   = (const float*)d_in[2];
  const float* ewv  = (const float*)d_in[3];
  const float* ebv  = (const float*)d_in[4];
  const float* egv  = (const float*)d_in[5];
  const float* ebbv = (const float*)d_in[6];
  const float* ewa  = (const float*)d_in[7];
  const float* eba  = (const float*)d_in[8];
  const float* ega  = (const float*)d_in[9];
  const float* ebba = (const float*)d_in[10];
  const float* ewt  = (const float*)d_in[11];
  const float* ebt  = (const float*)d_in[12];
  const float* egt  = (const float*)d_in[13];
  const float* ebbt = (const float*)d_in[14];
  const float* fw   = (const float*)d_in[15];
  const float* fb   = (const float*)d_in[16];
  const float* fg   = (const float*)d_in[17];
  const float* fbb  = (const float*)d_in[18];
  const float* rwq  = (const float*)d_in[19];
  const float* rwk  = (const float*)d_in[20];
  const float* rwv  = (const float*)d_in[21];
  const float* rwo  = (const float*)d_in[22];
  const float* rbq  = (const float*)d_in[23];
  const float* rbk  = (const float*)d_in[24];
  const float* rbv  = (const float*)d_in[25];
  const float* rbo  = (const float*)d_in[26];
  const float* rmem = (const float*)d_in[27];
  const float* grid = (const float*)d_in[28];
  const float* ow   = (const float*)d_in[29];
  const float* ob   = (const float*)d_in[30];

  ushort_t* wsu = (ushort_t*)d_ws;
  ushort_t* kvf = wsu + OFF_KV;
  float* wsf = (float*)((char*)d_ws + F32_BYTE_OFF);
  float* ggn = wsf;
  unsigned* cnt = (unsigned*)(wsf + 64);

  prep_weights<<<dim3(256), dim3(256), 0, stream>>>(ewv, ewa, ewt, fw, rwq, rwo, grid, wsu);
  prep_kv<<<dim3(120), dim3(256), 0, stream>>>(rwk, rwv, rbk, rbv, rmem, grid, kvf, ggn, cnt);
  arn_main<<<dim3(2048), dim3(256), 0, stream>>>(xv, xa, xt, wsu, kvf, ggn, cnt,
      ebv, egv, ebbv, eba, ega, ebba, ebt, egt, ebbt, fb, fg, fbb, rbq, rbo);
  arn_finish<<<dim3(1), dim3(192), 0, stream>>>(cnt, grid, ow, ob, (float*)d_out);
}

// Round 8
// 403.202 us; speedup vs baseline: 2.0774x; 1.2254x over previous
//
#include <hip/hip_runtime.h>
#include <hip/hip_bf16.h>
#include <math.h>

typedef unsigned short ushort_t;
typedef __attribute__((ext_vector_type(8))) short short8;
typedef __attribute__((ext_vector_type(4))) float f32x4;

#define B_TOTAL 131072

// ws layout (ushort element offsets). W blobs are K-split chunk-major:
// chunk = [N rows][32 k] where storage (n, slot s, j) holds logical
// k = ck*32 + 8*(s ^ SWZ(n)) + j.  Staged linearly via global_load_lds.
#define SWZ(n) ((((n) & 3)) ^ (((n) >> 2) & 3))
#define OFF_VIB 0        // 2 chunks  [192][32] = 12288
#define OFF_ACO 12288    // 8 chunks             = 49152
#define OFF_TMP 61440    // 4 chunks             = 24576
#define OFF_FUS 86016    // 18 chunks            = 110592
#define OFF_WQ 196608    // 18 chunks (layer-major)
#define OFF_WO 307200    // 18 chunks
#define OFF_GRID 417792  // 6 chunks [64][32]    = 12288
#define OFF_KV 430080    // 3 layers x 10240: Kb[4h][16s][64k] + Vt[4h][48d][32s]
#define F32_BYTE_OFF 921600

// prep kernels: keep explicit RTNE bit-twiddle (cold code)
__device__ __forceinline__ ushort_t f2bu_prep(float f) {
  union { float f; unsigned u; } c; c.f = f;
  unsigned u = c.u;
  unsigned r = (u + 0x7fffu + ((u >> 16) & 1u)) >> 16;  // RTNE
  return (ushort_t)r;
}
// hot kernel: single-instruction v_cvt_pk_bf16_f32 (also RTNE on gfx950)
__device__ __forceinline__ ushort_t f2bu(float f) {
  __hip_bfloat16 h = __float2bfloat16(f);
  return *(ushort_t*)&h;
}
__device__ __forceinline__ float fastrcp(float x) { return __builtin_amdgcn_rcpf(x); }
__device__ __forceinline__ float gelu_fast(float x) {
  float u = 0.7978845608f * x * (1.0f + 0.044715f * x * x);
  float E = exp2f(2.88539008f * u);
  float t = 1.0f - 2.0f * fastrcp(E + 1.0f);
  return 0.5f * x * (1.0f + t);
}
#define MFMA16(a, b, c) __builtin_amdgcn_mfma_f32_16x16x32_bf16(a, b, c, 0, 0, 0)

__device__ __forceinline__ void gload16(const void* g, void* l) {
  __builtin_amdgcn_global_load_lds((const __attribute__((address_space(1))) void*)g,
                                   (__attribute__((address_space(3))) void*)l, 16, 0, 0);
}

// ---------------- prep: weights -> K-split swizzled chunks ----------------
__global__ void prep_weights(const float* __restrict__ ev, const float* __restrict__ ea,
                             const float* __restrict__ et, const float* __restrict__ fw,
                             const float* __restrict__ rwq, const float* __restrict__ rwo,
                             const float* __restrict__ gr, ushort_t* __restrict__ ws) {
  int tid = blockIdx.x * blockDim.x + threadIdx.x;
  int nth = gridDim.x * blockDim.x;
  // vib: 2 chunks [192][32]; src ev [64][192]
  for (int i = tid; i < 12288; i += nth) {
    int ck = i / 6144, rem = i % 6144, n = rem >> 5, s = (rem >> 3) & 3, j = i & 7;
    int k = ck * 32 + 8 * (s ^ SWZ(n)) + j;
    ws[OFF_VIB + i] = f2bu_prep(ev[k * 192 + n]);
  }
  // aco: 8 chunks; src ea [256][192]
  for (int i = tid; i < 49152; i += nth) {
    int ck = i / 6144, rem = i % 6144, n = rem >> 5, s = (rem >> 3) & 3, j = i & 7;
    int k = ck * 32 + 8 * (s ^ SWZ(n)) + j;
    ws[OFF_ACO + i] = f2bu_prep(ea[k * 192 + n]);
  }
  // tmp: 4 chunks; src et [128][192]
  for (int i = tid; i < 24576; i += nth) {
    int ck = i / 6144, rem = i % 6144, n = rem >> 5, s = (rem >> 3) & 3, j = i & 7;
    int k = ck * 32 + 8 * (s ^ SWZ(n)) + j;
    ws[OFF_TMP + i] = f2bu_prep(et[k * 192 + n]);
  }
  // fus: 18 chunks; src fw [576][192]
  for (int i = tid; i < 110592; i += nth) {
    int ck = i / 6144, rem = i % 6144, n = rem >> 5, s = (rem >> 3) & 3, j = i & 7;
    int k = ck * 32 + 8 * (s ^ SWZ(n)) + j;
    ws[OFF_FUS + i] = f2bu_prep(fw[k * 192 + n]);
  }
  // wq/wo: 18 chunks each, 6 per layer
  for (int i = tid; i < 110592; i += nth) {
    int ck = i / 6144, rem = i % 6144, n = rem >> 5, s = (rem >> 3) & 3, j = i & 7;
    int l = ck / 6;
    int k = (ck % 6) * 32 + 8 * (s ^ SWZ(n)) + j;
    ws[OFF_WQ + i] = f2bu_prep(rwq[l * 36864 + k * 192 + n]);
    ws[OFF_WO + i] = f2bu_prep(rwo[l * 36864 + k * 192 + n]);
  }
  // grid: 6 chunks [64][32]; src gr [64][192] (B[n=g][k=d])
  for (int i = tid; i < 12288; i += nth) {
    int ck = i / 2048, rem = i % 2048, n = rem >> 5, s = (rem >> 3) & 3, j = i & 7;
    int k = ck * 32 + 8 * (s ^ SWZ(n)) + j;
    ws[OFF_GRID + i] = f2bu_prep(gr[n * 192 + k]);
  }
}

// ------- prep: K/V operand banks (plain layout, read from global) ---------
__global__ void prep_kv(const float* __restrict__ rwk, const float* __restrict__ rwv,
                        const float* __restrict__ rbk, const float* __restrict__ rbv,
                        const float* __restrict__ rmem, const float* __restrict__ gr,
                        ushort_t* __restrict__ kvf, float* __restrict__ ggn,
                        unsigned* __restrict__ cnt) {
  int tid = blockIdx.x * blockDim.x + threadIdx.x;
  int nth = gridDim.x * blockDim.x;
  // Kb[i][h][s(16)][k(64; k>=48 zero)]
  for (int idx = tid; idx < 12288; idx += nth) {
    int i = idx >> 12, r = idx & 4095, h = r >> 10, s = (r >> 6) & 15, k = r & 63;
    float val = 0.f;
    if (k < 48) {
      int d = h * 48 + k;
      const float* w = rwk + i * 36864;
      const float* mm = rmem + i * 3072 + s * 192;
      float acc = rbk[i * 192 + d];
      for (int kk = 0; kk < 192; ++kk) acc += mm[kk] * w[kk * 192 + d];
      val = acc;
    }
    kvf[i * 10240 + h * 1024 + s * 64 + k] = f2bu_prep(val);
  }
  // Vt[i][h][d(48)][s(32; s>=16 zero)]
  for (int idx = tid; idx < 18432; idx += nth) {
    int i = idx / 6144, r = idx % 6144, h = r / 1536, q = r % 1536, d = q >> 5, s = q & 31;
    float val = 0.f;
    if (s < 16) {
      int dd = h * 48 + d;
      const float* w = rwv + i * 36864;
      const float* mm = rmem + i * 3072 + s * 192;
      float acc = rbv[i * 192 + dd];
      for (int kk = 0; kk < 192; ++kk) acc += mm[kk] * w[kk * 192 + dd];
      val = acc;
    }
    kvf[i * 10240 + 4096 + h * 1536 + d * 32 + s] = f2bu_prep(val);
  }
  for (int g = tid; g < 64; g += nth) {
    const float* gp = gr + g * 192;
    float s = 0.f;
    for (int k = 0; k < 192; ++k) s += gp[k] * gp[k];
    ggn[g] = s;
    cnt[g] = 0u;
  }
}

// ---------------- main-kernel helpers ----------------
__device__ __forceinline__ void stage_to(ushort_t* dst, const ushort_t* src, int n16,
                                         int wave, int lane) {
  for (int j = 0; j < n16; ++j) {
    int seg = (wave * n16 + j) << 9;  // 512 ushorts = 1KB per wave-issue
    gload16(src + seg + lane * 8, dst + seg);
  }
}

// consumption-order phase table
__device__ __forceinline__ const ushort_t* chunk_ptr(const ushort_t* wsu, int g, int* n16) {
  if (g < 2)            { *n16 = 3; return wsu + OFF_VIB + g * 6144; }
  g -= 2;  if (g < 6)   { *n16 = 3; return wsu + OFF_FUS + g * 6144; }
  g -= 6;  if (g < 8)   { *n16 = 3; return wsu + OFF_ACO + g * 6144; }
  g -= 8;  if (g < 6)   { *n16 = 3; return wsu + OFF_FUS + 36864 + g * 6144; }
  g -= 6;  if (g < 4)   { *n16 = 3; return wsu + OFF_TMP + g * 6144; }
  g -= 4;  if (g < 6)   { *n16 = 3; return wsu + OFF_FUS + 73728 + g * 6144; }
  g -= 6;  if (g < 36)  { int l = g / 12, r2 = g - l * 12;
    *n16 = 3;
    return (r2 < 6) ? (wsu + OFF_WQ + l * 36864 + r2 * 6144)
                    : (wsu + OFF_WO + l * 36864 + (r2 - 6) * 6144); }
  g -= 36; if (g < 6)   { *n16 = 1; return wsu + OFF_GRID + g * 2048; }
  *n16 = 0; return wsu;
}

__device__ __forceinline__ void phase_begin(const ushort_t* wsu, ushort_t (*Wb)[6144],
                                            int gph, int wave, int lane) {
  __syncthreads();
  int n16; const ushort_t* ns = chunk_ptr(wsu, gph + 1, &n16);
  if (n16) stage_to(&Wb[(gph + 1) & 1][0], ns, n16, wave, lane);
}

__device__ __forceinline__ short8 cvt8(float4 a, float4 b) {
  short8 v;
  v[0] = (short)f2bu(a.x); v[1] = (short)f2bu(a.y); v[2] = (short)f2bu(a.z); v[3] = (short)f2bu(a.w);
  v[4] = (short)f2bu(b.x); v[5] = (short)f2bu(b.y); v[6] = (short)f2bu(b.z); v[7] = (short)f2bu(b.w);
  return v;
}

// encoder GEMM: A streamed from global (fp32) with 1-phase register pipeline
template<int NPH>
__device__ __forceinline__ void enc_gemm(const float* __restrict__ x, int row0, int row1,
    const ushort_t* wsu, ushort_t (*Wb)[6144], int* gph, f32x4* accE,
    int wc0, int m, int gq, int wave, int lane) {
  const int KF = NPH * 32;
  float4 ca0 = *(const float4*)(x + (size_t)row0 * KF + gq * 8);
  float4 ca1 = *(const float4*)(x + (size_t)row0 * KF + gq * 8 + 4);
  float4 cb0 = *(const float4*)(x + (size_t)row1 * KF + gq * 8);
  float4 cb1 = *(const float4*)(x + (size_t)row1 * KF + gq * 8 + 4);
#pragma unroll
  for (int ph = 0; ph < NPH; ++ph) {
    phase_begin(wsu, Wb, *gph, wave, lane);
    const ushort_t* Wc = &Wb[*gph & 1][0];
    short8 a0 = cvt8(ca0, ca1);
    short8 a1 = cvt8(cb0, cb1);
    if (ph + 1 < NPH) {
      int ko = (ph + 1) * 32 + gq * 8;
      ca0 = *(const float4*)(x + (size_t)row0 * KF + ko);
      ca1 = *(const float4*)(x + (size_t)row0 * KF + ko + 4);
      cb0 = *(const float4*)(x + (size_t)row1 * KF + ko);
      cb1 = *(const float4*)(x + (size_t)row1 * KF + ko + 4);
    }
#pragma unroll
    for (int t = 0; t < 6; ++t) {
      int n = wc0 + t * 16 + m;
      short8 b = *(const short8*)(Wc + n * 32 + ((gq ^ SWZ(n)) << 3));
      accE[t]     = MFMA16(a0, b, accE[t]);
      accE[6 + t] = MFMA16(a1, b, accE[6 + t]);
    }
    ++*gph;
  }
}

// GEMM with A from the swizzled activation panel (6 phases, K=192)
__device__ __forceinline__ void lds_gemm(const ushort_t* Ab, const ushort_t* wsu,
    ushort_t (*Wb)[6144], int* gph, f32x4* acc, int wr0, int wc0, int m, int gq,
    int wave, int lane) {
#pragma unroll
  for (int ph = 0; ph < 6; ++ph) {
    phase_begin(wsu, Wb, *gph, wave, lane);
    const ushort_t* Wc = &Wb[*gph & 1][0];
    int r0 = wr0 + m, r1 = wr0 + 16 + m;
    short8 a0 = *(const short8*)(Ab + r0 * 192 + (((ph * 4 + gq) ^ (r0 & 7)) << 3));
    short8 a1 = *(const short8*)(Ab + r1 * 192 + (((ph * 4 + gq) ^ (r1 & 7)) << 3));
#pragma unroll
    for (int t = 0; t < 6; ++t) {
      int n = wc0 + t * 16 + m;
      short8 b = *(const short8*)(Wc + n * 32 + ((gq ^ SWZ(n)) << 3));
      acc[t]     = MFMA16(a0, b, acc[t]);
      acc[6 + t] = MFMA16(a1, b, acc[6 + t]);
    }
    ++*gph;
  }
}

// LN(+GELU) epilogue, col-split: cross-wave stats via 1KB scratch
__device__ __forceinline__ void ln_gelu_cs(f32x4* acc, const float* __restrict__ bias,
    const float* __restrict__ gam, const float* __restrict__ bet,
    ushort_t* __restrict__ Ab, float2 (*scr)[2], int wr0, int wc0, int colh,
    int m, int gq) {
#pragma unroll
  for (int t = 0; t < 12; ++t) {
    float bv = bias[wc0 + (t % 6) * 16 + m];
#pragma unroll
    for (int j = 0; j < 4; ++j) acc[t][j] += bv;
  }
#pragma unroll
  for (int mt = 0; mt < 2; ++mt)
#pragma unroll
    for (int j = 0; j < 4; ++j) {
      float s = 0.f, q = 0.f;
#pragma unroll
      for (int t = 0; t < 6; ++t) { float v = acc[mt * 6 + t][j]; s += v; q += v * v; }
#pragma unroll
      for (int off = 1; off < 16; off <<= 1) {
        s += __shfl_xor(s, off, 64);
        q += __shfl_xor(q, off, 64);
      }
      if (m == 0) scr[wr0 + mt * 16 + gq * 4 + j][colh] = (float2){s, q};
    }
  __syncthreads();
#pragma unroll
  for (int mt = 0; mt < 2; ++mt)
#pragma unroll
    for (int j = 0; j < 4; ++j) {
      int row = wr0 + mt * 16 + gq * 4 + j;
      float2 h0 = scr[row][0], h1 = scr[row][1];
      float mean = (h0.x + h1.x) * (1.0f / 192.0f);
      float var = (h0.y + h1.y) * (1.0f / 192.0f) - mean * mean;
      float rstd = rsqrtf(var + 1e-5f);
#pragma unroll
      for (int t = 0; t < 6; ++t) {
        int col = wc0 + t * 16 + m;
        float y = (acc[mt * 6 + t][j] - mean) * rstd * gam[col] + bet[col];
        Ab[row * 192 + ((((col >> 3) ^ (row & 7))) << 3) + (col & 7)] = f2bu(gelu_fast(y));
      }
    }
}

__device__ __forceinline__ void bias_store_cs(f32x4* acc, const float* __restrict__ bias,
    ushort_t* __restrict__ Ab, int wr0, int wc0, int m, int gq) {
#pragma unroll
  for (int mt = 0; mt < 2; ++mt)
#pragma unroll
    for (int t = 0; t < 6; ++t) {
      int col = wc0 + t * 16 + m;
      float bv = bias[col];
#pragma unroll
      for (int j = 0; j < 4; ++j) {
        int row = wr0 + mt * 16 + gq * 4 + j;
        Ab[row * 192 + ((((col >> 3) ^ (row & 7))) << 3) + (col & 7)] =
            f2bu(acc[mt * 6 + t][j] + bv);
      }
    }
}

// ---------------- main fused kernel ----------------
// R8: waves_per_eu(2) = min 2 (reg budget <=256, no spill) with NO max cap;
// VGPR=128 => occupancy becomes LDS-limited at 3 blocks/CU (R7's (2,2) cap
// pinned it at 2). Hot-path bf16 converts now use v_cvt_pk_bf16_f32.
__global__ __launch_bounds__(256) __attribute__((amdgpu_waves_per_eu(2))) void arn_main(
    const float* __restrict__ xv, const float* __restrict__ xa, const float* __restrict__ xt,
    const ushort_t* __restrict__ wsu, const ushort_t* __restrict__ kvf,
    const float* __restrict__ ggn, unsigned* __restrict__ counts,
    const float* __restrict__ ebv, const float* __restrict__ egv, const float* __restrict__ ebbv,
    const float* __restrict__ eba, const float* __restrict__ ega, const float* __restrict__ ebba,
    const float* __restrict__ ebt, const float* __restrict__ egt, const float* __restrict__ ebbt,
    const float* __restrict__ fb, const float* __restrict__ fg, const float* __restrict__ fbb,
    const float* __restrict__ rbq, const float* __restrict__ rbo) {
  __shared__ __align__(16) ushort_t Abuf[64 * 192 + 64];  // swizzled activations + zero pad
  __shared__ __align__(16) ushort_t Wbuf[2][6144];        // double-buffered W chunks
  __shared__ float2 lnscr[64][2];
  __shared__ float c_l[64];
  __shared__ unsigned hist[64];

  const int tid = threadIdx.x, lane = tid & 63, wave = tid >> 6;
  const int m = lane & 15, gq = lane >> 4;
  const int wr0 = (wave & 1) * 32;       // GEMM row half
  const int wc0 = (wave >> 1) * 96;      // GEMM col half
  const int colh = wave >> 1;
  const int aw0 = wave * 16;             // attention row base
  const int growbase = blockIdx.x * 64;

  if (tid < 64) { hist[tid] = 0u; c_l[tid] = 0.5f * ggn[tid]; Abuf[12288 + tid] = 0; }

  int gph = 0;
  { int n16; const ushort_t* s0 = chunk_ptr(wsu, 0, &n16); stage_to(&Wbuf[0][0], s0, n16, wave, lane); }

  const int row0 = growbase + wr0 + m, row1 = row0 + 16;
  f32x4 accF[12];
#pragma unroll
  for (int t = 0; t < 12; ++t) accF[t] = (f32x4){0.f, 0.f, 0.f, 0.f};

  // ===== vib encoder + fus part 0 =====
  {
    f32x4 accE[12];
#pragma unroll
    for (int t = 0; t < 12; ++t) accE[t] = (f32x4){0.f, 0.f, 0.f, 0.f};
    enc_gemm<2>(xv, row0, row1, wsu, Wbuf, &gph, accE, wc0, m, gq, wave, lane);
    ln_gelu_cs(accE, ebv, egv, ebbv, Abuf, lnscr, wr0, wc0, colh, m, gq);
  }
  lds_gemm(Abuf, wsu, Wbuf, &gph, accF, wr0, wc0, m, gq, wave, lane);

  // ===== aco encoder + fus part 1 =====
  {
    f32x4 accE[12];
#pragma unroll
    for (int t = 0; t < 12; ++t) accE[t] = (f32x4){0.f, 0.f, 0.f, 0.f};
    enc_gemm<8>(xa, row0, row1, wsu, Wbuf, &gph, accE, wc0, m, gq, wave, lane);
    ln_gelu_cs(accE, eba, ega, ebba, Abuf, lnscr, wr0, wc0, colh, m, gq);
  }
  lds_gemm(Abuf, wsu, Wbuf, &gph, accF, wr0, wc0, m, gq, wave, lane);

  // ===== tmp encoder + fus part 2 + fusion LN =====
  {
    f32x4 accE[12];
#pragma unroll
    for (int t = 0; t < 12; ++t) accE[t] = (f32x4){0.f, 0.f, 0.f, 0.f};
    enc_gemm<4>(xt, row0, row1, wsu, Wbuf, &gph, accE, wc0, m, gq, wave, lane);
    ln_gelu_cs(accE, ebt, egt, ebbt, Abuf, lnscr, wr0, wc0, colh, m, gq);
  }
  lds_gemm(Abuf, wsu, Wbuf, &gph, accF, wr0, wc0, m, gq, wave, lane);
  ln_gelu_cs(accF, fb, fg, fbb, Abuf, lnscr, wr0, wc0, colh, m, gq);

  // ===== 3 resonance layers =====
  for (int i = 0; i < 3; ++i) {
    {
      f32x4 accQ[12];
#pragma unroll
      for (int t = 0; t < 12; ++t) accQ[t] = (f32x4){0.f, 0.f, 0.f, 0.f};
      lds_gemm(Abuf, wsu, Wbuf, &gph, accQ, wr0, wc0, m, gq, wave, lane);
      bias_store_cs(accQ, rbq + i * 192, Abuf, wr0, wc0, m, gq);
    }
    __syncthreads();  // Q visible to all waves; P-buffer (Wbuf[1]) free
    {
      const ushort_t* kvl = kvf + i * 10240;
      ushort_t* Pw = &Wbuf[1][0] + wave * 512;  // [16 rows][32 slots]
      // zero pad slots 16..31 (8B per lane)
      *(uint2*)(Pw + (lane >> 2) * 32 + 16 + (lane & 3) * 4) = (uint2){0u, 0u};
      const float scale = 0.144337567297406441f;  // 1/sqrt(48)
#pragma unroll
      for (int h = 0; h < 4; ++h) {
        f32x4 s4 = (f32x4){0.f, 0.f, 0.f, 0.f};
#pragma unroll
        for (int ks = 0; ks < 2; ++ks) {
          int kg = h * 6 + ks * 4 + gq;
          int r = aw0 + m;
          short8 a = *(const short8*)(Abuf + r * 192 + ((kg ^ (r & 7)) << 3));
          short8 b = *(const short8*)(kvl + h * 1024 + m * 64 + ks * 32 + gq * 8);
          s4 = MFMA16(a, b, s4);
        }
#pragma unroll
        for (int j = 0; j < 4; ++j) {
          float v = s4[j] * scale;
          float mx = v;
          mx = fmaxf(mx, __shfl_xor(mx, 1, 64));
          mx = fmaxf(mx, __shfl_xor(mx, 2, 64));
          mx = fmaxf(mx, __shfl_xor(mx, 4, 64));
          mx = fmaxf(mx, __shfl_xor(mx, 8, 64));
          float e = exp2f((v - mx) * 1.44269504f);
          float sm = e;
          sm += __shfl_xor(sm, 1, 64);
          sm += __shfl_xor(sm, 2, 64);
          sm += __shfl_xor(sm, 4, 64);
          sm += __shfl_xor(sm, 8, 64);
          Pw[(gq * 4 + j) * 32 + m] = f2bu(e * fastrcp(sm));
        }
        short8 pa = *(const short8*)(Pw + m * 32 + gq * 8);
#pragma unroll
        for (int t = 0; t < 3; ++t) {
          short8 vb = *(const short8*)(kvl + 4096 + h * 1536 + (t * 16 + m) * 32 + gq * 8);
          f32x4 o4 = MFMA16(pa, vb, ((f32x4){0.f, 0.f, 0.f, 0.f}));
          int col = h * 48 + t * 16 + m;
#pragma unroll
          for (int j = 0; j < 4; ++j) {
            int row = aw0 + gq * 4 + j;
            Abuf[row * 192 + ((((col >> 3) ^ (row & 7))) << 3) + (col & 7)] = f2bu(o4[j]);
          }
        }
      }
    }
    {
      f32x4 accO[12];
#pragma unroll
      for (int t = 0; t < 12; ++t) accO[t] = (f32x4){0.f, 0.f, 0.f, 0.f};
      lds_gemm(Abuf, wsu, Wbuf, &gph, accO, wr0, wc0, m, gq, wave, lane);
      bias_store_cs(accO, rbo + i * 192, Abuf, wr0, wc0, m, gq);
    }
  }

  // ===== SOFM: argmax_g (f.g - ||g||^2/2) -> histogram =====
  {
    f32x4 accS[8];
#pragma unroll
    for (int t = 0; t < 8; ++t) accS[t] = (f32x4){0.f, 0.f, 0.f, 0.f};
#pragma unroll
    for (int ph = 0; ph < 6; ++ph) {
      phase_begin(wsu, Wbuf, gph, wave, lane);
      const ushort_t* Wc = &Wbuf[gph & 1][0];
      int r0 = wr0 + m, r1 = wr0 + 16 + m;
      short8 a0 = *(const short8*)(Abuf + r0 * 192 + (((ph * 4 + gq) ^ (r0 & 7)) << 3));
      short8 a1 = *(const short8*)(Abuf + r1 * 192 + (((ph * 4 + gq) ^ (r1 & 7)) << 3));
#pragma unroll
      for (int nt = 0; nt < 4; ++nt) {
        int n = nt * 16 + m;
        short8 b = *(const short8*)(Wc + n * 32 + ((gq ^ SWZ(n)) << 3));
        accS[nt]     = MFMA16(a0, b, accS[nt]);
        accS[4 + nt] = MFMA16(a1, b, accS[4 + nt]);
      }
      ++gph;
    }
#pragma unroll
    for (int mt = 0; mt < 2; ++mt)
#pragma unroll
      for (int j = 0; j < 4; ++j) {
        float bv = -3.0e38f; int bi = 0;
#pragma unroll
        for (int nt = 0; nt < 4; ++nt) {
          int g = nt * 16 + m;
          float v = accS[mt * 4 + nt][j] - c_l[g];
          bool take = (v > bv);
          bv = take ? v : bv; bi = take ? g : bi;
        }
#pragma unroll
        for (int off = 1; off < 16; off <<= 1) {
          float ov = __shfl_xor(bv, off, 64);
          int oi = __shfl_xor(bi, off, 64);
          bool take = (ov > bv) || (ov == bv && oi < bi);
          bv = take ? ov : bv; bi = take ? oi : bi;
        }
        // both col-half waves compute the same rows' argmax; only colh==0 counts
        if (m == 0 && colh == 0) atomicAdd(&hist[bi], 1u);
      }
  }
  __syncthreads();
  if (tid < 64 && hist[tid]) atomicAdd(&counts[tid], hist[tid]);
}

// ---------------- finisher ----------------
__global__ void arn_finish(const unsigned* __restrict__ counts, const float* __restrict__ gr,
                           const float* __restrict__ ow, const float* __restrict__ ob,
                           float* __restrict__ out) {
  __shared__ float pooled[192];
  __shared__ float cf[64];
  int t = threadIdx.x;
  if (t < 64) cf[t] = (float)counts[t];
  __syncthreads();
  float s = 0.f;
  for (int g = 0; g < 64; ++g) s += cf[g] * gr[g * 192 + t];
  pooled[t] = s * (1.0f / (float)B_TOTAL);
  __syncthreads();
  if (t < 6) {
    float o = ob[t];
    for (int j = 0; j < 192; ++j) o += pooled[j] * ow[j * 6 + t];
    out[t] = (t == 1) ? fmaxf(o, 0.f) : 1.f / (1.f + expf(-o));
  }
}

// ---------------- launch ----------------
extern "C" void kernel_launch(void* const* d_in, const int* in_sizes, int n_in,
                              void* d_out, int out_size, void* d_ws, size_t ws_size,
                              hipStream_t stream) {
  (void)in_sizes; (void)n_in; (void)out_size; (void)ws_size;
  const float* xv   = (const float*)d_in[0];
  const float* xa   = (const float*)d_in[1];
  const float* xt   = (const float*)d_in[2];
  const float* ewv  = (const float*)d_in[3];
  const float* ebv  = (const float*)d_in[4];
  const float* egv  = (const float*)d_in[5];
  const float* ebbv = (const float*)d_in[6];
  const float* ewa  = (const float*)d_in[7];
  const float* eba  = (const float*)d_in[8];
  const float* ega  = (const float*)d_in[9];
  const float* ebba = (const float*)d_in[10];
  const float* ewt  = (const float*)d_in[11];
  const float* ebt  = (const float*)d_in[12];
  const float* egt  = (const float*)d_in[13];
  const float* ebbt = (const float*)d_in[14];
  const float* fw   = (const float*)d_in[15];
  const float* fb   = (const float*)d_in[16];
  const float* fg   = (const float*)d_in[17];
  const float* fbb  = (const float*)d_in[18];
  const float* rwq  = (const float*)d_in[19];
  const float* rwk  = (const float*)d_in[20];
  const float* rwv  = (const float*)d_in[21];
  const float* rwo  = (const float*)d_in[22];
  const float* rbq  = (const float*)d_in[23];
  const float* rbk  = (const float*)d_in[24];
  const float* rbv  = (const float*)d_in[25];
  const float* rbo  = (const float*)d_in[26];
  const float* rmem = (const float*)d_in[27];
  const float* grid = (const float*)d_in[28];
  const float* ow   = (const float*)d_in[29];
  const float* ob   = (const float*)d_in[30];

  ushort_t* wsu = (ushort_t*)d_ws;
  ushort_t* kvf = wsu + OFF_KV;
  float* wsf = (float*)((char*)d_ws + F32_BYTE_OFF);
  float* ggn = wsf;
  unsigned* cnt = (unsigned*)(wsf + 64);

  prep_weights<<<dim3(256), dim3(256), 0, stream>>>(ewv, ewa, ewt, fw, rwq, rwo, grid, wsu);
  prep_kv<<<dim3(120), dim3(256), 0, stream>>>(rwk, rwv, rbk, rbv, rmem, grid, kvf, ggn, cnt);
  arn_main<<<dim3(2048), dim3(256), 0, stream>>>(xv, xa, xt, wsu, kvf, ggn, cnt,
      ebv, egv, ebbv, eba, ega, ebba, ebt, egt, ebbt, fb, fg, fbb, rbq, rbo);
  arn_finish<<<dim3(1), dim3(192), 0, stream>>>(cnt, grid, ow, ob, (float*)d_out);
}